// Round 10
// baseline (240.832 us; speedup 1.0000x reference)
//
#include <hip/hip_runtime.h>

static inline int ceil_div(int a, int b) { return (a + b - 1) / b; }

typedef __attribute__((ext_vector_type(8))) short short8;   // 8 bf16 = 4 VGPR
typedef __attribute__((ext_vector_type(4))) float f32x4;

__device__ __forceinline__ ushort bf16_rne(float v) {
  uint u = __float_as_uint(v);
  return (ushort)((u + 0x7FFFu + ((u >> 16) & 1u)) >> 16);
}

// ---------------- CSR build ----------------

__global__ void k_zero_int(int* __restrict__ p, int n) {
  int i = blockIdx.x * blockDim.x + threadIdx.x;
  if (i < n) p[i] = 0;
}

#define SCAN_BS 256
#define SCAN_VPT 4
#define SCAN_CHUNK (SCAN_BS * SCAN_VPT)

__global__ __launch_bounds__(SCAN_BS) void k_blocksum(const int* __restrict__ cnt,
                                                      int* __restrict__ partial, int n) {
  __shared__ int s[SCAN_BS / 64];
  const int tid = threadIdx.x;
  const int base = blockIdx.x * SCAN_CHUNK;
  int sum = 0;
#pragma unroll
  for (int j = 0; j < SCAN_VPT; ++j) {
    int i = base + tid + j * SCAN_BS;
    if (i < n) sum += cnt[i];
  }
#pragma unroll
  for (int off = 32; off > 0; off >>= 1) sum += __shfl_down(sum, off, 64);
  if ((tid & 63) == 0) s[tid >> 6] = sum;
  __syncthreads();
  if (tid == 0) {
    int t = 0;
#pragma unroll
    for (int w = 0; w < SCAN_BS / 64; ++w) t += s[w];
    partial[blockIdx.x] = t;
  }
}

__global__ __launch_bounds__(256) void k_scan_partials(int* __restrict__ partial, int p,
                                                       int* __restrict__ row_ptr, int n_nodes) {
  __shared__ int s[256];
  const int tid = threadIdx.x;
  int carry = 0;
  for (int base = 0; base < p; base += 256) {
    int i = base + tid;
    int v = (i < p) ? partial[i] : 0;
    s[tid] = v;
    __syncthreads();
    for (int off = 1; off < 256; off <<= 1) {
      int t = (tid >= off) ? s[tid - off] : 0;
      __syncthreads();
      s[tid] += t;
      __syncthreads();
    }
    if (i < p) partial[i] = carry + s[tid] - v;  // exclusive
    int tot = s[255];
    __syncthreads();
    carry += tot;
  }
  if (tid == 0) row_ptr[n_nodes] = carry;
}

__global__ __launch_bounds__(SCAN_BS) void k_scatter(const int* __restrict__ cnt,
                                                     const int* __restrict__ partial,
                                                     int* __restrict__ row_ptr,
                                                     float* __restrict__ inv, int n) {
  __shared__ int s[SCAN_BS];
  const int tid = threadIdx.x;
  const int base = blockIdx.x * SCAN_CHUNK;
  const int i0 = base + tid * SCAN_VPT;
  int v[SCAN_VPT];
  int cv[SCAN_VPT];
  int sum = 0;
#pragma unroll
  for (int j = 0; j < SCAN_VPT; ++j) {
    int i = i0 + j;
    int c = (i < n) ? cnt[i] : 0;
    cv[j] = c;
    v[j] = sum;
    sum += c;
  }
  s[tid] = sum;
  __syncthreads();
  for (int off = 1; off < SCAN_BS; off <<= 1) {
    int t = (tid >= off) ? s[tid - off] : 0;
    __syncthreads();
    s[tid] += t;
    __syncthreads();
  }
  const int excl = partial[blockIdx.x] + s[tid] - sum;
#pragma unroll
  for (int j = 0; j < SCAN_VPT; ++j) {
    int i = i0 + j;
    if (i < n) {
      row_ptr[i] = excl + v[j];
      inv[i] = 1.0f / (float)(cv[j] > 1 ? cv[j] : 1);
    }
  }
}

// place edges: csr16[row_ptr[dst] + rank] = (ushort)src ; no atomics
__global__ void k_place(const int* __restrict__ src, const int* __restrict__ dst,
                        const int* __restrict__ rank, const int* __restrict__ row_ptr,
                        ushort* __restrict__ csr16, int e) {
  int i0 = (blockIdx.x * blockDim.x + threadIdx.x) * 4;
  if (i0 >= e) return;
  if (i0 + 3 < e) {
    int4 dv = *(const int4*)(dst + i0);
    int4 sv = *(const int4*)(src + i0);
    int4 rv = *(const int4*)(rank + i0);
    int p0 = row_ptr[dv.x], p1 = row_ptr[dv.y], p2 = row_ptr[dv.z], p3 = row_ptr[dv.w];
    csr16[p0 + rv.x] = (ushort)sv.x;
    csr16[p1 + rv.y] = (ushort)sv.y;
    csr16[p2 + rv.z] = (ushort)sv.z;
    csr16[p3 + rv.w] = (ushort)sv.w;
  } else {
#pragma unroll
    for (int j = 0; j < 4; ++j) {
      int i = i0 + j;
      if (i < e) csr16[row_ptr[dst[i]] + rank[i]] = (ushort)src[i];
    }
  }
}

// -------- weight pack: split fp32 W into hi/lo bf16, MFMA-B-fragment order ----
template <int FOUT>
__global__ void k_pack(const float* __restrict__ Wl, const float* __restrict__ Wr,
                       ushort* __restrict__ hi, ushort* __restrict__ lo) {
  constexpr int NCOL = 2 * FOUT;
  constexpr int NCHUNK = 4 * NCOL * 4;
  int ct = blockIdx.x * 256 + threadIdx.x;
  if (ct >= NCHUNK) return;
  const int g = ct & 3;
  const int nn = (ct >> 2) % NCOL;
  const int kt = ct / (4 * NCOL);
  uint hw[4], lw[4];
#pragma unroll
  for (int w = 0; w < 4; ++w) {
    uint h2[2], l2[2];
#pragma unroll
    for (int t = 0; t < 2; ++t) {
      int j = 2 * w + t;
      int k = kt * 32 + g * 8 + j;
      float v = (nn < FOUT) ? Wl[k * FOUT + nn] : Wr[k * FOUT + (nn - FOUT)];
      uint u = __float_as_uint(v);
      uint h = u >> 16;
      float r = v - __uint_as_float(h << 16);
      uint l = __float_as_uint(r) >> 16;
      h2[t] = h; l2[t] = l;
    }
    hw[w] = h2[0] | (h2[1] << 16);
    lw[w] = l2[0] | (l2[1] << 16);
  }
  ((uint4*)hi)[ct] = make_uint4(hw[0], hw[1], hw[2], hw[3]);
  ((uint4*)lo)[ct] = make_uint4(lw[0], lw[1], lw[2], lw[3]);
}

// ==== fused: [blocks 0..G) layer-0 split-bf16 GEMM (64 rows) | [G..) count_rank
// The count_rank pass (latency-bound atomics) hides under the GEMM's MFMA+L2
// traffic -- complementary pipes, no shared resources except L2 slots.
__global__ __launch_bounds__(256) void k_gemm0_count(
    const float* __restrict__ hin, const ushort* __restrict__ Whi,
    const ushort* __restrict__ Wlo, const float* __restrict__ bias,
    ushort* __restrict__ Zb, float* __restrict__ R, int n, int gemmBlocks,
    const int* __restrict__ dstv, int* __restrict__ cnt, int* __restrict__ rank, int e) {
  constexpr int FOUT = 128;
  constexpr int NCOL = 2 * FOUT;
  constexpr int NT = NCOL / 64;  // 4
  constexpr int MT = 4;          // 64 rows/block
  __shared__ uint4 sA[2][64 * 16];  // 32KB: [hi/lo][row][slot]

  const int tid = threadIdx.x;

  if (blockIdx.x >= gemmBlocks) {
    // ---------------- count_rank path ----------------
    int i0 = ((blockIdx.x - gemmBlocks) * 256 + tid) * 4;
    if (i0 >= e) return;
    int d[4], r[4];
    if (i0 + 3 < e) {
      int4 dv = *(const int4*)(dstv + i0);
      d[0] = dv.x; d[1] = dv.y; d[2] = dv.z; d[3] = dv.w;
    } else {
#pragma unroll
      for (int j = 0; j < 4; ++j) d[j] = (i0 + j < e) ? dstv[i0 + j] : 0;
    }
#pragma unroll
    for (int j = 0; j < 4; ++j)
      if (i0 + j < e) r[j] = atomicAdd(&cnt[d[j]], 1);
    if (i0 + 3 < e) {
      *(int4*)(rank + i0) = make_int4(r[0], r[1], r[2], r[3]);
    } else {
#pragma unroll
      for (int j = 0; j < 4; ++j)
        if (i0 + j < e) rank[i0 + j] = r[j];
    }
    return;
  }

  // ---------------- layer-0 GEMM path ----------------
  const int lane = tid & 63;
  const int wave = tid >> 6;
  const int row0 = blockIdx.x * 64;

  // stage 64x128 fp32 -> hi/lo bf16 in LDS (4 threads/row, 32 floats each)
  {
    const int srow = tid >> 2;  // 0..63
    const int kc = tid & 3;     // 32-float chunk
    float4 f4[8];
    int g = row0 + srow;
    if (g < n) {
      const float4* hp = (const float4*)(hin + (size_t)g * 128 + kc * 32);
#pragma unroll
      for (int w = 0; w < 8; ++w) f4[w] = hp[w];
    } else {
#pragma unroll
      for (int w = 0; w < 8; ++w) f4[w] = make_float4(0.f, 0.f, 0.f, 0.f);
    }
    const float* fp = (const float*)f4;
#pragma unroll
    for (int b = 0; b < 4; ++b) {
      uint hw[4], lw[4];
#pragma unroll
      for (int w = 0; w < 4; ++w) {
        float a0 = fp[b * 8 + 2 * w], a1 = fp[b * 8 + 2 * w + 1];
        uint u0 = __float_as_uint(a0), u1 = __float_as_uint(a1);
        uint h0 = u0 >> 16, h1 = u1 >> 16;
        float r0 = a0 - __uint_as_float(h0 << 16);
        float r1 = a1 - __uint_as_float(h1 << 16);
        uint l0 = __float_as_uint(r0) >> 16, l1 = __float_as_uint(r1) >> 16;
        hw[w] = h0 | (h1 << 16);
        lw[w] = l0 | (l1 << 16);
      }
      int slot = (kc * 4 + b) ^ (srow & 7);
      sA[0][srow * 16 + slot] = make_uint4(hw[0], hw[1], hw[2], hw[3]);
      sA[1][srow * 16 + slot] = make_uint4(lw[0], lw[1], lw[2], lw[3]);
    }
  }
  __syncthreads();

  const int n0 = wave * (NCOL / 4);
  const int g16 = lane >> 4;   // k-group 0..3
  const int l16 = lane & 15;

  f32x4 acc[MT][NT];
#pragma unroll
  for (int mt = 0; mt < MT; ++mt)
#pragma unroll
    for (int nt = 0; nt < NT; ++nt) acc[mt][nt] = (f32x4)(0.f);

#pragma unroll
  for (int kt = 0; kt < 4; ++kt) {
    short8 ahi[MT], alo[MT];
#pragma unroll
    for (int mt = 0; mt < MT; ++mt) {
      int row = mt * 16 + l16;
      int slot = (kt * 4 + g16) ^ (row & 7);
      ahi[mt] = *(const short8*)&sA[0][row * 16 + slot];
      alo[mt] = *(const short8*)&sA[1][row * 16 + slot];
    }
    short8 bh[NT];
#pragma unroll
    for (int nt = 0; nt < NT; ++nt) {
      size_t chunk = (size_t)(kt * NCOL + n0 + nt * 16 + l16) * 4 + g16;
      bh[nt] = *(const short8*)(Whi + chunk * 8);
    }
#pragma unroll
    for (int mt = 0; mt < MT; ++mt)
#pragma unroll
      for (int nt = 0; nt < NT; ++nt)
        acc[mt][nt] = __builtin_amdgcn_mfma_f32_16x16x32_bf16(ahi[mt], bh[nt], acc[mt][nt], 0, 0, 0);
#pragma unroll
    for (int mt = 0; mt < MT; ++mt)
#pragma unroll
      for (int nt = 0; nt < NT; ++nt)
        acc[mt][nt] = __builtin_amdgcn_mfma_f32_16x16x32_bf16(alo[mt], bh[nt], acc[mt][nt], 0, 0, 0);
    short8 bl[NT];
#pragma unroll
    for (int nt = 0; nt < NT; ++nt) {
      size_t chunk = (size_t)(kt * NCOL + n0 + nt * 16 + l16) * 4 + g16;
      bl[nt] = *(const short8*)(Wlo + chunk * 8);
    }
#pragma unroll
    for (int mt = 0; mt < MT; ++mt)
#pragma unroll
      for (int nt = 0; nt < NT; ++nt)
        acc[mt][nt] = __builtin_amdgcn_mfma_f32_16x16x32_bf16(ahi[mt], bl[nt], acc[mt][nt], 0, 0, 0);
  }

  // epilogue: C/D layout col=lane&15, row=(lane>>4)*4+j
#pragma unroll
  for (int nt = 0; nt < NT; ++nt) {
    int col = n0 + nt * 16 + l16;
    bool isR = col >= FOUT;
    int cw = isR ? col - FOUT : col;
    float badd = isR ? bias[cw] : 0.f;
#pragma unroll
    for (int mt = 0; mt < MT; ++mt) {
#pragma unroll
      for (int j = 0; j < 4; ++j) {
        int row = row0 + mt * 16 + g16 * 4 + j;
        if (row < n) {
          float v = acc[mt][nt][j] + badd;
          if (isR) R[(size_t)row * FOUT + cw] = v;
          else Zb[(size_t)row * FOUT + cw] = bf16_rne(v);
        }
      }
    }
  }
}

// -------- layers 1/2: A bf16, LDS-staged dual GEMM, 64 rows/block (MT=4) -----
// R9 lesson: 32-row blocks were L2-latency-bound on weight loads (only ~80cy
// MFMA per kt to hide ~200cy). MT=4 doubles MFMA work per weight fetch.
template <int FOUT>
__global__ __launch_bounds__(256) void k_gemm2b(const ushort* __restrict__ Hb,
                                                const ushort* __restrict__ Whi,
                                                const ushort* __restrict__ Wlo,
                                                const float* __restrict__ bias,
                                                ushort* __restrict__ Zb,
                                                float* __restrict__ R, int n) {
  constexpr int NCOL = 2 * FOUT;
  constexpr int NT = NCOL / 64;
  constexpr int MT = 4;
  __shared__ uint4 sA[64 * 16];  // 16KB: 64 rows x 16 slots of 16B

  const int tid = threadIdx.x;
  const int lane = tid & 63;
  const int wave = tid >> 6;
  const int row0 = blockIdx.x * 64;

#pragma unroll
  for (int c = tid; c < 1024; c += 256) {
    int srow = c >> 4, col16 = c & 15;
    int g = row0 + srow;
    uint4 v = make_uint4(0u, 0u, 0u, 0u);
    if (g < n) v = *(const uint4*)(Hb + (size_t)g * 128 + col16 * 8);
    sA[srow * 16 + (col16 ^ (srow & 7))] = v;
  }
  __syncthreads();

  const int n0 = wave * (NCOL / 4);
  const int g16 = lane >> 4;
  const int l16 = lane & 15;

  f32x4 acc[MT][NT];
#pragma unroll
  for (int mt = 0; mt < MT; ++mt)
#pragma unroll
    for (int nt = 0; nt < NT; ++nt) acc[mt][nt] = (f32x4)(0.f);

#pragma unroll
  for (int kt = 0; kt < 4; ++kt) {
    short8 a[MT];
#pragma unroll
    for (int mt = 0; mt < MT; ++mt) {
      int row = mt * 16 + l16;
      int slot = (kt * 4 + g16) ^ (row & 7);
      a[mt] = *(const short8*)&sA[row * 16 + slot];
    }
    short8 bh[NT], bl[NT];
#pragma unroll
    for (int nt = 0; nt < NT; ++nt) {
      size_t chunk = (size_t)(kt * NCOL + n0 + nt * 16 + l16) * 4 + g16;
      bh[nt] = *(const short8*)(Whi + chunk * 8);
      bl[nt] = *(const short8*)(Wlo + chunk * 8);
    }
#pragma unroll
    for (int mt = 0; mt < MT; ++mt)
#pragma unroll
      for (int nt = 0; nt < NT; ++nt)
        acc[mt][nt] = __builtin_amdgcn_mfma_f32_16x16x32_bf16(a[mt], bh[nt], acc[mt][nt], 0, 0, 0);
#pragma unroll
    for (int mt = 0; mt < MT; ++mt)
#pragma unroll
      for (int nt = 0; nt < NT; ++nt)
        acc[mt][nt] = __builtin_amdgcn_mfma_f32_16x16x32_bf16(a[mt], bl[nt], acc[mt][nt], 0, 0, 0);
  }

#pragma unroll
  for (int nt = 0; nt < NT; ++nt) {
    int col = n0 + nt * 16 + l16;
    bool isR = col >= FOUT;
    int cw = isR ? col - FOUT : col;
    float badd = isR ? bias[cw] : 0.f;
#pragma unroll
    for (int mt = 0; mt < MT; ++mt) {
#pragma unroll
      for (int j = 0; j < 4; ++j) {
        int row = row0 + mt * 16 + g16 * 4 + j;
        if (row < n) {
          float v = acc[mt][nt][j] + badd;
          if (isR) R[(size_t)row * FOUT + cw] = v;
          else Zb[(size_t)row * FOUT + cw] = bf16_rne(v);
        }
      }
    }
  }
}

// -------- CSR mean-aggregation + epilogue: out = act(mean(Zb)*inv + R) --------
// OUTB: write bf16 H (16B/lane) for middle layers; fp32 for the final output.
template <int FOUT, bool RELU, bool OUTB>
__global__ __launch_bounds__(256) void k_agg2(const ushort* __restrict__ Zb,
                                              const float* __restrict__ R,
                                              const int* __restrict__ row_ptr,
                                              const ushort* __restrict__ csr16,
                                              const float* __restrict__ inv,
                                              void* __restrict__ outp, int n) {
  constexpr int FL = FOUT / 8;  // lanes per row (16 or 8)
  constexpr int EG = 64 / FL;   // edge groups per wave (4 or 8)
  const int lane = threadIdx.x & 63;
  const int node = blockIdx.x * 4 + (threadIdx.x >> 6);
  if (node >= n) return;
  const int c = lane % FL;
  const int eg = lane / FL;

  const int e0 = row_ptr[node];
  const int m = row_ptr[node + 1] - e0;  // wave-uniform
  const uint4* Z4 = (const uint4*)Zb;    // 16B = 8 bf16

  float acc[8];
#pragma unroll
  for (int k = 0; k < 8; ++k) acc[k] = 0.f;

  int t = eg;
  while (t < m) {
    int ss[4];
#pragma unroll
    for (int j = 0; j < 4; ++j) {
      int tj = t + j * EG;
      int tc = (tj < m) ? tj : (m - 1);  // clamped: always valid
      ss[j] = csr16[e0 + tc];
    }
    uint4 z[4];
#pragma unroll
    for (int j = 0; j < 4; ++j) z[j] = Z4[(size_t)ss[j] * FL + c];
#pragma unroll
    for (int j = 0; j < 4; ++j) {
      if (t + j * EG < m) {
        const uint* zw = (const uint*)&z[j];
#pragma unroll
        for (int w = 0; w < 4; ++w) {
          acc[2 * w]     += __uint_as_float(zw[w] << 16);
          acc[2 * w + 1] += __uint_as_float(zw[w] & 0xFFFF0000u);
        }
      }
    }
    t += 4 * EG;
  }

#pragma unroll
  for (int off = FL; off < 64; off <<= 1) {
#pragma unroll
    for (int k = 0; k < 8; ++k) acc[k] += __shfl_xor(acc[k], off, 64);
  }

  if (eg == 0) {
    const float iv = inv[node];
    const float4* Rp = (const float4*)(R + (size_t)node * FOUT + c * 8);
    float4 r0 = Rp[0], r1 = Rp[1];
    float o[8];
    o[0] = fmaf(acc[0], iv, r0.x);
    o[1] = fmaf(acc[1], iv, r0.y);
    o[2] = fmaf(acc[2], iv, r0.z);
    o[3] = fmaf(acc[3], iv, r0.w);
    o[4] = fmaf(acc[4], iv, r1.x);
    o[5] = fmaf(acc[5], iv, r1.y);
    o[6] = fmaf(acc[6], iv, r1.z);
    o[7] = fmaf(acc[7], iv, r1.w);
    if (RELU) {
#pragma unroll
      for (int k = 0; k < 8; ++k) o[k] = fmaxf(o[k], 0.f);
    }
    if (OUTB) {
      uint p[4];
#pragma unroll
      for (int w = 0; w < 4; ++w)
        p[w] = (uint)bf16_rne(o[2 * w]) | ((uint)bf16_rne(o[2 * w + 1]) << 16);
      ((uint4*)outp)[(size_t)node * FL + c] = make_uint4(p[0], p[1], p[2], p[3]);
    } else {
      float4* op = (float4*)((float*)outp + (size_t)node * FOUT + c * 8);
      op[0] = make_float4(o[0], o[1], o[2], o[3]);
      op[1] = make_float4(o[4], o[5], o[6], o[7]);
    }
  }
}

// ---------------- launch ----------------

extern "C" void kernel_launch(void* const* d_in, const int* in_sizes, int n_in,
                              void* d_out, int out_size, void* d_ws, size_t ws_size,
                              hipStream_t stream) {
  const float* x   = (const float*)d_in[0];
  const int*   ei  = (const int*)d_in[1];
  const float* Wl0 = (const float*)d_in[2];
  const float* bl0 = (const float*)d_in[3];
  const float* Wr0 = (const float*)d_in[4];
  const float* Wl1 = (const float*)d_in[5];
  const float* bl1 = (const float*)d_in[6];
  const float* Wr1 = (const float*)d_in[7];
  const float* Wl2 = (const float*)d_in[8];
  const float* bl2 = (const float*)d_in[9];
  const float* Wr2 = (const float*)d_in[10];
  float* out = (float*)d_out;

  const int N = in_sizes[0] / 128;
  const int E = in_sizes[1] / 2;
  const int* src = ei;
  const int* dst = ei + E;

  char* w = (char*)d_ws;
  auto alloc = [&](size_t bytes) {
    char* p = w;
    w += (bytes + 255) & ~(size_t)255;
    return p;
  };
  int*    cnt     = (int*)alloc((size_t)N * 4);
  int*    row_ptr = (int*)alloc((size_t)(N + 1) * 4);
  int*    rank    = (int*)alloc((size_t)E * 4);
  ushort* csr16   = (ushort*)alloc((size_t)E * 2 + 256);
  float*  inv     = (float*)alloc((size_t)N * 4);
  int*    partial = (int*)alloc((size_t)ceil_div(N, SCAN_CHUNK) * 4 + 256);
  ushort* Whi0    = (ushort*)alloc((size_t)4 * 256 * 4 * 16);
  ushort* Wlo0    = (ushort*)alloc((size_t)4 * 256 * 4 * 16);
  ushort* Whi1    = (ushort*)alloc((size_t)4 * 256 * 4 * 16);
  ushort* Wlo1    = (ushort*)alloc((size_t)4 * 256 * 4 * 16);
  ushort* Whi2    = (ushort*)alloc((size_t)4 * 128 * 4 * 16);
  ushort* Wlo2    = (ushort*)alloc((size_t)4 * 128 * 4 * 16);
  ushort* BZ      = (ushort*)alloc((size_t)N * 128 * 2);
  float*  BR      = (float*)alloc((size_t)N * 128 * 4);
  ushort* B0      = (ushort*)alloc((size_t)N * 128 * 2);  // H in bf16
  (void)ws_size; (void)n_in; (void)out_size;

  const int P = ceil_div(N, SCAN_CHUNK);
  const int G0 = ceil_div(N, 64);      // gemm blocks (64 rows each)
  const int C0 = ceil_div(E, 1024);    // count_rank blocks

  // ---- weight packs ----
  k_pack<128><<<16, 256, 0, stream>>>(Wl0, Wr0, Whi0, Wlo0);
  k_pack<128><<<16, 256, 0, stream>>>(Wl1, Wr1, Whi1, Wlo1);
  k_pack<64><<<8, 256, 0, stream>>>(Wl2, Wr2, Whi2, Wlo2);

  // ---- zero degree histogram, then fused [layer-0 GEMM | count_rank] ----
  k_zero_int<<<ceil_div(N, 256), 256, 0, stream>>>(cnt, N);
  k_gemm0_count<<<G0 + C0, 256, 0, stream>>>(x, Whi0, Wlo0, bl0, BZ, BR, N, G0,
                                             dst, cnt, rank, E);

  // ---- rest of CSR build ----
  k_blocksum<<<P, SCAN_BS, 0, stream>>>(cnt, partial, N);
  k_scan_partials<<<1, 256, 0, stream>>>(partial, P, row_ptr, N);
  k_scatter<<<P, SCAN_BS, 0, stream>>>(cnt, partial, row_ptr, inv, N);
  k_place<<<ceil_div(E, 1024), 256, 0, stream>>>(src, dst, rank, row_ptr, csr16, E);

  // ---- layer 0 aggregation -> H1 bf16 (B0) ----
  k_agg2<128, true, true><<<ceil_div(N, 4), 256, 0, stream>>>(BZ, BR, row_ptr, csr16, inv, B0, N);

  // ---- layer 1: H1 bf16 -> (Zb,R) -> H2 bf16 (B0) ----
  k_gemm2b<128><<<ceil_div(N, 64), 256, 0, stream>>>(B0, Whi1, Wlo1, bl1, BZ, BR, N);
  k_agg2<128, true, true><<<ceil_div(N, 4), 256, 0, stream>>>(BZ, BR, row_ptr, csr16, inv, B0, N);

  // ---- layer 2: H2 bf16 -> (Zb,R) 64-wide -> out fp32 ----
  k_gemm2b<64><<<ceil_div(N, 64), 256, 0, stream>>>(B0, Whi2, Wlo2, bl2, BZ, BR, N);
  k_agg2<64, false, false><<<ceil_div(N, 4), 256, 0, stream>>>(BZ, BR, row_ptr, csr16, inv, out, N);
}

// Round 11
// 234.390 us; speedup vs baseline: 1.0275x; 1.0275x over previous
//
#include <hip/hip_runtime.h>

static inline int ceil_div(int a, int b) { return (a + b - 1) / b; }

typedef __attribute__((ext_vector_type(8))) short short8;   // 8 bf16 = 4 VGPR
typedef __attribute__((ext_vector_type(4))) float f32x4;

__device__ __forceinline__ ushort bf16_rne(float v) {
  uint u = __float_as_uint(v);
  return (ushort)((u + 0x7FFFu + ((u >> 16) & 1u)) >> 16);
}

// ---------------- CSR build ----------------

__global__ void k_zero_int(int* __restrict__ p, int n) {
  int i = blockIdx.x * blockDim.x + threadIdx.x;
  if (i < n) p[i] = 0;
}

// histogram + per-edge rank (coalesced int4 loads/stores, 4 atomics in flight)
__global__ void k_count_rank(const int* __restrict__ dst, int* __restrict__ cnt,
                             int* __restrict__ rank, int e) {
  int i0 = (blockIdx.x * blockDim.x + threadIdx.x) * 4;
  if (i0 >= e) return;
  int d[4], r[4];
  if (i0 + 3 < e) {
    int4 dv = *(const int4*)(dst + i0);
    d[0] = dv.x; d[1] = dv.y; d[2] = dv.z; d[3] = dv.w;
  } else {
#pragma unroll
    for (int j = 0; j < 4; ++j) d[j] = (i0 + j < e) ? dst[i0 + j] : 0;
  }
#pragma unroll
  for (int j = 0; j < 4; ++j)
    if (i0 + j < e) r[j] = atomicAdd(&cnt[d[j]], 1);
  if (i0 + 3 < e) {
    *(int4*)(rank + i0) = make_int4(r[0], r[1], r[2], r[3]);
  } else {
#pragma unroll
    for (int j = 0; j < 4; ++j)
      if (i0 + j < e) rank[i0 + j] = r[j];
  }
}

#define SCAN_BS 256
#define SCAN_VPT 4
#define SCAN_CHUNK (SCAN_BS * SCAN_VPT)

__global__ __launch_bounds__(SCAN_BS) void k_blocksum(const int* __restrict__ cnt,
                                                      int* __restrict__ partial, int n) {
  __shared__ int s[SCAN_BS / 64];
  const int tid = threadIdx.x;
  const int base = blockIdx.x * SCAN_CHUNK;
  int sum = 0;
#pragma unroll
  for (int j = 0; j < SCAN_VPT; ++j) {
    int i = base + tid + j * SCAN_BS;
    if (i < n) sum += cnt[i];
  }
#pragma unroll
  for (int off = 32; off > 0; off >>= 1) sum += __shfl_down(sum, off, 64);
  if ((tid & 63) == 0) s[tid >> 6] = sum;
  __syncthreads();
  if (tid == 0) {
    int t = 0;
#pragma unroll
    for (int w = 0; w < SCAN_BS / 64; ++w) t += s[w];
    partial[blockIdx.x] = t;
  }
}

__global__ __launch_bounds__(256) void k_scan_partials(int* __restrict__ partial, int p,
                                                       int* __restrict__ row_ptr, int n_nodes) {
  __shared__ int s[256];
  const int tid = threadIdx.x;
  int carry = 0;
  for (int base = 0; base < p; base += 256) {
    int i = base + tid;
    int v = (i < p) ? partial[i] : 0;
    s[tid] = v;
    __syncthreads();
    for (int off = 1; off < 256; off <<= 1) {
      int t = (tid >= off) ? s[tid - off] : 0;
      __syncthreads();
      s[tid] += t;
      __syncthreads();
    }
    if (i < p) partial[i] = carry + s[tid] - v;  // exclusive
    int tot = s[255];
    __syncthreads();
    carry += tot;
  }
  if (tid == 0) row_ptr[n_nodes] = carry;
}

__global__ __launch_bounds__(SCAN_BS) void k_scatter(const int* __restrict__ cnt,
                                                     const int* __restrict__ partial,
                                                     int* __restrict__ row_ptr,
                                                     float* __restrict__ inv, int n) {
  __shared__ int s[SCAN_BS];
  const int tid = threadIdx.x;
  const int base = blockIdx.x * SCAN_CHUNK;
  const int i0 = base + tid * SCAN_VPT;
  int v[SCAN_VPT];
  int cv[SCAN_VPT];
  int sum = 0;
#pragma unroll
  for (int j = 0; j < SCAN_VPT; ++j) {
    int i = i0 + j;
    int c = (i < n) ? cnt[i] : 0;
    cv[j] = c;
    v[j] = sum;
    sum += c;
  }
  s[tid] = sum;
  __syncthreads();
  for (int off = 1; off < SCAN_BS; off <<= 1) {
    int t = (tid >= off) ? s[tid - off] : 0;
    __syncthreads();
    s[tid] += t;
    __syncthreads();
  }
  const int excl = partial[blockIdx.x] + s[tid] - sum;
#pragma unroll
  for (int j = 0; j < SCAN_VPT; ++j) {
    int i = i0 + j;
    if (i < n) {
      row_ptr[i] = excl + v[j];
      inv[i] = 1.0f / (float)(cv[j] > 1 ? cv[j] : 1);
    }
  }
}

// place edges: csr16[row_ptr[dst] + rank] = (ushort)src ; no atomics
__global__ void k_place(const int* __restrict__ src, const int* __restrict__ dst,
                        const int* __restrict__ rank, const int* __restrict__ row_ptr,
                        ushort* __restrict__ csr16, int e) {
  int i0 = (blockIdx.x * blockDim.x + threadIdx.x) * 4;
  if (i0 >= e) return;
  if (i0 + 3 < e) {
    int4 dv = *(const int4*)(dst + i0);
    int4 sv = *(const int4*)(src + i0);
    int4 rv = *(const int4*)(rank + i0);
    int p0 = row_ptr[dv.x], p1 = row_ptr[dv.y], p2 = row_ptr[dv.z], p3 = row_ptr[dv.w];
    csr16[p0 + rv.x] = (ushort)sv.x;
    csr16[p1 + rv.y] = (ushort)sv.y;
    csr16[p2 + rv.z] = (ushort)sv.z;
    csr16[p3 + rv.w] = (ushort)sv.w;
  } else {
#pragma unroll
    for (int j = 0; j < 4; ++j) {
      int i = i0 + j;
      if (i < e) csr16[row_ptr[dst[i]] + rank[i]] = (ushort)src[i];
    }
  }
}

// -------- weight pack: split fp32 W into hi/lo bf16, MFMA-B-fragment order ----
template <int FOUT>
__global__ void k_pack(const float* __restrict__ Wl, const float* __restrict__ Wr,
                       ushort* __restrict__ hi, ushort* __restrict__ lo) {
  constexpr int NCOL = 2 * FOUT;
  constexpr int NCHUNK = 4 * NCOL * 4;
  int ct = blockIdx.x * 256 + threadIdx.x;
  if (ct >= NCHUNK) return;
  const int g = ct & 3;
  const int nn = (ct >> 2) % NCOL;
  const int kt = ct / (4 * NCOL);
  uint hw[4], lw[4];
#pragma unroll
  for (int w = 0; w < 4; ++w) {
    uint h2[2], l2[2];
#pragma unroll
    for (int t = 0; t < 2; ++t) {
      int j = 2 * w + t;
      int k = kt * 32 + g * 8 + j;
      float v = (nn < FOUT) ? Wl[k * FOUT + nn] : Wr[k * FOUT + (nn - FOUT)];
      uint u = __float_as_uint(v);
      uint h = u >> 16;
      float r = v - __uint_as_float(h << 16);
      uint l = __float_as_uint(r) >> 16;
      h2[t] = h; l2[t] = l;
    }
    hw[w] = h2[0] | (h2[1] << 16);
    lw[w] = l2[0] | (l2[1] << 16);
  }
  ((uint4*)hi)[ct] = make_uint4(hw[0], hw[1], hw[2], hw[3]);
  ((uint4*)lo)[ct] = make_uint4(lw[0], lw[1], lw[2], lw[3]);
}

// -------- layer-0 split-bf16 MFMA dual GEMM (A = fp32): Z(bf16), R(fp32)+b ----
// R10 lesson: do NOT fuse atomics storms into this kernel -- the epilogue's
// 64B half-line stores rely on quiet L2 write-combining.
template <int FOUT>
__global__ __launch_bounds__(256) void k_gemm2(const float* __restrict__ hin,
                                               const ushort* __restrict__ Whi,
                                               const ushort* __restrict__ Wlo,
                                               const float* __restrict__ bias,
                                               ushort* __restrict__ Zb,
                                               float* __restrict__ R, int n) {
  constexpr int NCOL = 2 * FOUT;
  constexpr int NT = NCOL / 64;  // n-tiles per wave
  constexpr int MT = 2;          // m-tiles (32 rows)
  __shared__ uint4 sA[2][32 * 16];  // [hi/lo][row][slot] 16B slots

  const int tid = threadIdx.x;
  const int lane = tid & 63;
  const int wave = tid >> 6;
  const int row0 = blockIdx.x * 32;

  // ---- stage 32x128 fp32 -> hi/lo bf16 in LDS ----
  {
    const int srow = tid >> 3;  // 0..31
    const int kc = tid & 7;     // 16-float chunk
    float4 f4[4];
    int g = row0 + srow;
    if (g < n) {
      const float4* hp = (const float4*)(hin + (size_t)g * 128 + kc * 16);
      f4[0] = hp[0]; f4[1] = hp[1]; f4[2] = hp[2]; f4[3] = hp[3];
    } else {
      f4[0] = f4[1] = f4[2] = f4[3] = make_float4(0.f, 0.f, 0.f, 0.f);
    }
    const float* fp = (const float*)f4;
#pragma unroll
    for (int b = 0; b < 2; ++b) {
      uint hw[4], lw[4];
#pragma unroll
      for (int w = 0; w < 4; ++w) {
        float a0 = fp[b * 8 + 2 * w], a1 = fp[b * 8 + 2 * w + 1];
        uint u0 = __float_as_uint(a0), u1 = __float_as_uint(a1);
        uint h0 = u0 >> 16, h1 = u1 >> 16;
        float r0 = a0 - __uint_as_float(h0 << 16);
        float r1 = a1 - __uint_as_float(h1 << 16);
        uint l0 = __float_as_uint(r0) >> 16, l1 = __float_as_uint(r1) >> 16;
        hw[w] = h0 | (h1 << 16);
        lw[w] = l0 | (l1 << 16);
      }
      int slot = (kc * 2 + b) ^ (srow & 7);
      sA[0][srow * 16 + slot] = make_uint4(hw[0], hw[1], hw[2], hw[3]);
      sA[1][srow * 16 + slot] = make_uint4(lw[0], lw[1], lw[2], lw[3]);
    }
  }
  __syncthreads();

  const int n0 = wave * (NCOL / 4);
  const int g16 = lane >> 4;   // k-group 0..3
  const int l16 = lane & 15;

  f32x4 acc[MT][NT];
#pragma unroll
  for (int mt = 0; mt < MT; ++mt)
#pragma unroll
    for (int nt = 0; nt < NT; ++nt) acc[mt][nt] = (f32x4)(0.f);

#pragma unroll
  for (int kt = 0; kt < 4; ++kt) {
    short8 ahi[MT], alo[MT];
#pragma unroll
    for (int mt = 0; mt < MT; ++mt) {
      int row = mt * 16 + l16;
      int slot = (kt * 4 + g16) ^ (row & 7);
      ahi[mt] = *(const short8*)&sA[0][row * 16 + slot];
      alo[mt] = *(const short8*)&sA[1][row * 16 + slot];
    }
    short8 bh[NT];
#pragma unroll
    for (int nt = 0; nt < NT; ++nt) {
      size_t chunk = (size_t)(kt * NCOL + n0 + nt * 16 + l16) * 4 + g16;
      bh[nt] = *(const short8*)(Whi + chunk * 8);
    }
#pragma unroll
    for (int mt = 0; mt < MT; ++mt)
#pragma unroll
      for (int nt = 0; nt < NT; ++nt)
        acc[mt][nt] = __builtin_amdgcn_mfma_f32_16x16x32_bf16(ahi[mt], bh[nt], acc[mt][nt], 0, 0, 0);
#pragma unroll
    for (int mt = 0; mt < MT; ++mt)
#pragma unroll
      for (int nt = 0; nt < NT; ++nt)
        acc[mt][nt] = __builtin_amdgcn_mfma_f32_16x16x32_bf16(alo[mt], bh[nt], acc[mt][nt], 0, 0, 0);
    short8 bl[NT];
#pragma unroll
    for (int nt = 0; nt < NT; ++nt) {
      size_t chunk = (size_t)(kt * NCOL + n0 + nt * 16 + l16) * 4 + g16;
      bl[nt] = *(const short8*)(Wlo + chunk * 8);
    }
#pragma unroll
    for (int mt = 0; mt < MT; ++mt)
#pragma unroll
      for (int nt = 0; nt < NT; ++nt)
        acc[mt][nt] = __builtin_amdgcn_mfma_f32_16x16x32_bf16(ahi[mt], bl[nt], acc[mt][nt], 0, 0, 0);
  }

  // ---- epilogue: C/D layout col=lane&15, row=(lane>>4)*4+j ----
#pragma unroll
  for (int nt = 0; nt < NT; ++nt) {
    int col = n0 + nt * 16 + l16;
    bool isR = col >= FOUT;
    int cw = isR ? col - FOUT : col;
    float badd = isR ? bias[cw] : 0.f;
#pragma unroll
    for (int mt = 0; mt < MT; ++mt) {
#pragma unroll
      for (int j = 0; j < 4; ++j) {
        int row = row0 + mt * 16 + g16 * 4 + j;
        if (row < n) {
          float v = acc[mt][nt][j] + badd;
          if (isR) R[(size_t)row * FOUT + cw] = v;
          else Zb[(size_t)row * FOUT + cw] = bf16_rne(v);
        }
      }
    }
  }
}

// -------- layers 1/2: A bf16, LDS-staged dual GEMM, 64 rows/block (MT=4) -----
// MT=4 doubles MFMA work per weight fetch (R9 lesson: weight L2 latency-bound).
// Staging is bank-balanced: each bank gets exactly 8 accesses per wave-store.
template <int FOUT>
__global__ __launch_bounds__(256) void k_gemm2b(const ushort* __restrict__ Hb,
                                                const ushort* __restrict__ Whi,
                                                const ushort* __restrict__ Wlo,
                                                const float* __restrict__ bias,
                                                ushort* __restrict__ Zb,
                                                float* __restrict__ R, int n) {
  constexpr int NCOL = 2 * FOUT;
  constexpr int NT = NCOL / 64;
  constexpr int MT = 4;
  __shared__ uint4 sA[64 * 16];  // 16KB: 64 rows x 16 slots of 16B

  const int tid = threadIdx.x;
  const int lane = tid & 63;
  const int wave = tid >> 6;
  const int row0 = blockIdx.x * 64;

#pragma unroll
  for (int c = tid; c < 1024; c += 256) {
    int srow = c >> 4, col16 = c & 15;
    int g = row0 + srow;
    uint4 v = make_uint4(0u, 0u, 0u, 0u);
    if (g < n) v = *(const uint4*)(Hb + (size_t)g * 128 + col16 * 8);
    sA[srow * 16 + (col16 ^ (srow & 7))] = v;
  }
  __syncthreads();

  const int n0 = wave * (NCOL / 4);
  const int g16 = lane >> 4;
  const int l16 = lane & 15;

  f32x4 acc[MT][NT];
#pragma unroll
  for (int mt = 0; mt < MT; ++mt)
#pragma unroll
    for (int nt = 0; nt < NT; ++nt) acc[mt][nt] = (f32x4)(0.f);

#pragma unroll
  for (int kt = 0; kt < 4; ++kt) {
    short8 a[MT];
#pragma unroll
    for (int mt = 0; mt < MT; ++mt) {
      int row = mt * 16 + l16;
      int slot = (kt * 4 + g16) ^ (row & 7);
      a[mt] = *(const short8*)&sA[row * 16 + slot];
    }
    short8 bh[NT], bl[NT];
#pragma unroll
    for (int nt = 0; nt < NT; ++nt) {
      size_t chunk = (size_t)(kt * NCOL + n0 + nt * 16 + l16) * 4 + g16;
      bh[nt] = *(const short8*)(Whi + chunk * 8);
      bl[nt] = *(const short8*)(Wlo + chunk * 8);
    }
#pragma unroll
    for (int mt = 0; mt < MT; ++mt)
#pragma unroll
      for (int nt = 0; nt < NT; ++nt)
        acc[mt][nt] = __builtin_amdgcn_mfma_f32_16x16x32_bf16(a[mt], bh[nt], acc[mt][nt], 0, 0, 0);
#pragma unroll
    for (int mt = 0; mt < MT; ++mt)
#pragma unroll
      for (int nt = 0; nt < NT; ++nt)
        acc[mt][nt] = __builtin_amdgcn_mfma_f32_16x16x32_bf16(a[mt], bl[nt], acc[mt][nt], 0, 0, 0);
  }

#pragma unroll
  for (int nt = 0; nt < NT; ++nt) {
    int col = n0 + nt * 16 + l16;
    bool isR = col >= FOUT;
    int cw = isR ? col - FOUT : col;
    float badd = isR ? bias[cw] : 0.f;
#pragma unroll
    for (int mt = 0; mt < MT; ++mt) {
#pragma unroll
      for (int j = 0; j < 4; ++j) {
        int row = row0 + mt * 16 + g16 * 4 + j;
        if (row < n) {
          float v = acc[mt][nt][j] + badd;
          if (isR) R[(size_t)row * FOUT + cw] = v;
          else Zb[(size_t)row * FOUT + cw] = bf16_rne(v);
        }
      }
    }
  }
}

// -------- CSR mean-aggregation + epilogue: out = act(mean(Zb)*inv + R) --------
// OUTB: write bf16 H (16B/lane) for middle layers; fp32 for the final output.
template <int FOUT, bool RELU, bool OUTB>
__global__ __launch_bounds__(256) void k_agg2(const ushort* __restrict__ Zb,
                                              const float* __restrict__ R,
                                              const int* __restrict__ row_ptr,
                                              const ushort* __restrict__ csr16,
                                              const float* __restrict__ inv,
                                              void* __restrict__ outp, int n) {
  constexpr int FL = FOUT / 8;  // lanes per row (16 or 8)
  constexpr int EG = 64 / FL;   // edge groups per wave (4 or 8)
  const int lane = threadIdx.x & 63;
  const int node = blockIdx.x * 4 + (threadIdx.x >> 6);
  if (node >= n) return;
  const int c = lane % FL;
  const int eg = lane / FL;

  const int e0 = row_ptr[node];
  const int m = row_ptr[node + 1] - e0;  // wave-uniform
  const uint4* Z4 = (const uint4*)Zb;    // 16B = 8 bf16

  float acc[8];
#pragma unroll
  for (int k = 0; k < 8; ++k) acc[k] = 0.f;

  int t = eg;
  while (t < m) {
    int ss[4];
#pragma unroll
    for (int j = 0; j < 4; ++j) {
      int tj = t + j * EG;
      int tc = (tj < m) ? tj : (m - 1);  // clamped: always valid
      ss[j] = csr16[e0 + tc];
    }
    uint4 z[4];
#pragma unroll
    for (int j = 0; j < 4; ++j) z[j] = Z4[(size_t)ss[j] * FL + c];
#pragma unroll
    for (int j = 0; j < 4; ++j) {
      if (t + j * EG < m) {
        const uint* zw = (const uint*)&z[j];
#pragma unroll
        for (int w = 0; w < 4; ++w) {
          acc[2 * w]     += __uint_as_float(zw[w] << 16);
          acc[2 * w + 1] += __uint_as_float(zw[w] & 0xFFFF0000u);
        }
      }
    }
    t += 4 * EG;
  }

#pragma unroll
  for (int off = FL; off < 64; off <<= 1) {
#pragma unroll
    for (int k = 0; k < 8; ++k) acc[k] += __shfl_xor(acc[k], off, 64);
  }

  if (eg == 0) {
    const float iv = inv[node];
    const float4* Rp = (const float4*)(R + (size_t)node * FOUT + c * 8);
    float4 r0 = Rp[0], r1 = Rp[1];
    float o[8];
    o[0] = fmaf(acc[0], iv, r0.x);
    o[1] = fmaf(acc[1], iv, r0.y);
    o[2] = fmaf(acc[2], iv, r0.z);
    o[3] = fmaf(acc[3], iv, r0.w);
    o[4] = fmaf(acc[4], iv, r1.x);
    o[5] = fmaf(acc[5], iv, r1.y);
    o[6] = fmaf(acc[6], iv, r1.z);
    o[7] = fmaf(acc[7], iv, r1.w);
    if (RELU) {
#pragma unroll
      for (int k = 0; k < 8; ++k) o[k] = fmaxf(o[k], 0.f);
    }
    if (OUTB) {
      uint p[4];
#pragma unroll
      for (int w = 0; w < 4; ++w)
        p[w] = (uint)bf16_rne(o[2 * w]) | ((uint)bf16_rne(o[2 * w + 1]) << 16);
      ((uint4*)outp)[(size_t)node * FL + c] = make_uint4(p[0], p[1], p[2], p[3]);
    } else {
      float4* op = (float4*)((float*)outp + (size_t)node * FOUT + c * 8);
      op[0] = make_float4(o[0], o[1], o[2], o[3]);
      op[1] = make_float4(o[4], o[5], o[6], o[7]);
    }
  }
}

// ---------------- launch ----------------

extern "C" void kernel_launch(void* const* d_in, const int* in_sizes, int n_in,
                              void* d_out, int out_size, void* d_ws, size_t ws_size,
                              hipStream_t stream) {
  const float* x   = (const float*)d_in[0];
  const int*   ei  = (const int*)d_in[1];
  const float* Wl0 = (const float*)d_in[2];
  const float* bl0 = (const float*)d_in[3];
  const float* Wr0 = (const float*)d_in[4];
  const float* Wl1 = (const float*)d_in[5];
  const float* bl1 = (const float*)d_in[6];
  const float* Wr1 = (const float*)d_in[7];
  const float* Wl2 = (const float*)d_in[8];
  const float* bl2 = (const float*)d_in[9];
  const float* Wr2 = (const float*)d_in[10];
  float* out = (float*)d_out;

  const int N = in_sizes[0] / 128;
  const int E = in_sizes[1] / 2;
  const int* src = ei;
  const int* dst = ei + E;

  char* w = (char*)d_ws;
  auto alloc = [&](size_t bytes) {
    char* p = w;
    w += (bytes + 255) & ~(size_t)255;
    return p;
  };
  int*    cnt     = (int*)alloc((size_t)N * 4);
  int*    row_ptr = (int*)alloc((size_t)(N + 1) * 4);
  int*    rank    = (int*)alloc((size_t)E * 4);
  ushort* csr16   = (ushort*)alloc((size_t)E * 2 + 256);
  float*  inv     = (float*)alloc((size_t)N * 4);
  int*    partial = (int*)alloc((size_t)ceil_div(N, SCAN_CHUNK) * 4 + 256);
  ushort* Whi0    = (ushort*)alloc((size_t)4 * 256 * 4 * 16);
  ushort* Wlo0    = (ushort*)alloc((size_t)4 * 256 * 4 * 16);
  ushort* Whi1    = (ushort*)alloc((size_t)4 * 256 * 4 * 16);
  ushort* Wlo1    = (ushort*)alloc((size_t)4 * 256 * 4 * 16);
  ushort* Whi2    = (ushort*)alloc((size_t)4 * 128 * 4 * 16);
  ushort* Wlo2    = (ushort*)alloc((size_t)4 * 128 * 4 * 16);
  ushort* BZ      = (ushort*)alloc((size_t)N * 128 * 2);
  float*  BR      = (float*)alloc((size_t)N * 128 * 4);
  ushort* B0      = (ushort*)alloc((size_t)N * 128 * 2);  // H in bf16
  (void)ws_size; (void)n_in; (void)out_size;

  const int P = ceil_div(N, SCAN_CHUNK);

  // ---- weight packs ----
  k_pack<128><<<16, 256, 0, stream>>>(Wl0, Wr0, Whi0, Wlo0);
  k_pack<128><<<16, 256, 0, stream>>>(Wl1, Wr1, Whi1, Wlo1);
  k_pack<64><<<8, 256, 0, stream>>>(Wl2, Wr2, Whi2, Wlo2);

  // ---- CSR build (rank-based, single atomic pass) ----
  k_zero_int<<<ceil_div(N, 256), 256, 0, stream>>>(cnt, N);
  k_count_rank<<<ceil_div(E, 1024), 256, 0, stream>>>(dst, cnt, rank, E);
  k_blocksum<<<P, SCAN_BS, 0, stream>>>(cnt, partial, N);
  k_scan_partials<<<1, 256, 0, stream>>>(partial, P, row_ptr, N);
  k_scatter<<<P, SCAN_BS, 0, stream>>>(cnt, partial, row_ptr, inv, N);
  k_place<<<ceil_div(E, 1024), 256, 0, stream>>>(src, dst, rank, row_ptr, csr16, E);

  // ---- layer 0: x (fp32) -> (Zb,R) -> H1 bf16 (B0) ----
  k_gemm2<128><<<ceil_div(N, 32), 256, 0, stream>>>(x, Whi0, Wlo0, bl0, BZ, BR, N);
  k_agg2<128, true, true><<<ceil_div(N, 4), 256, 0, stream>>>(BZ, BR, row_ptr, csr16, inv, B0, N);

  // ---- layer 1: H1 bf16 -> (Zb,R) -> H2 bf16 (B0) ----
  k_gemm2b<128><<<ceil_div(N, 64), 256, 0, stream>>>(B0, Whi1, Wlo1, bl1, BZ, BR, N);
  k_agg2<128, true, true><<<ceil_div(N, 4), 256, 0, stream>>>(BZ, BR, row_ptr, csr16, inv, B0, N);

  // ---- layer 2: H2 bf16 -> (Zb,R) 64-wide -> out fp32 ----
  k_gemm2b<64><<<ceil_div(N, 64), 256, 0, stream>>>(B0, Whi2, Wlo2, bl2, BZ, BR, N);
  k_agg2<64, false, false><<<ceil_div(N, 4), 256, 0, stream>>>(BZ, BR, row_ptr, csr16, inv, out, N);
}

// Round 12
// 224.696 us; speedup vs baseline: 1.0718x; 1.0431x over previous
//
#include <hip/hip_runtime.h>

static inline int ceil_div(int a, int b) { return (a + b - 1) / b; }

typedef __attribute__((ext_vector_type(8))) short short8;   // 8 bf16 = 4 VGPR
typedef __attribute__((ext_vector_type(4))) float f32x4;

__device__ __forceinline__ ushort bf16_rne(float v) {
  uint u = __float_as_uint(v);
  return (ushort)((u + 0x7FFFu + ((u >> 16) & 1u)) >> 16);
}

// ---------------- CSR build ----------------

__global__ void k_zero_int(int* __restrict__ p, int n) {
  int i = blockIdx.x * blockDim.x + threadIdx.x;
  if (i < n) p[i] = 0;
}

// histogram + per-edge rank (coalesced int4 loads/stores, 4 atomics in flight)
__global__ void k_count_rank(const int* __restrict__ dst, int* __restrict__ cnt,
                             int* __restrict__ rank, int e) {
  int i0 = (blockIdx.x * blockDim.x + threadIdx.x) * 4;
  if (i0 >= e) return;
  int d[4], r[4];
  if (i0 + 3 < e) {
    int4 dv = *(const int4*)(dst + i0);
    d[0] = dv.x; d[1] = dv.y; d[2] = dv.z; d[3] = dv.w;
  } else {
#pragma unroll
    for (int j = 0; j < 4; ++j) d[j] = (i0 + j < e) ? dst[i0 + j] : 0;
  }
#pragma unroll
  for (int j = 0; j < 4; ++j)
    if (i0 + j < e) r[j] = atomicAdd(&cnt[d[j]], 1);
  if (i0 + 3 < e) {
    *(int4*)(rank + i0) = make_int4(r[0], r[1], r[2], r[3]);
  } else {
#pragma unroll
    for (int j = 0; j < 4; ++j)
      if (i0 + j < e) rank[i0 + j] = r[j];
  }
}

#define SCAN_BS 256
#define SCAN_VPT 4
#define SCAN_CHUNK (SCAN_BS * SCAN_VPT)

__global__ __launch_bounds__(SCAN_BS) void k_blocksum(const int* __restrict__ cnt,
                                                      int* __restrict__ partial, int n) {
  __shared__ int s[SCAN_BS / 64];
  const int tid = threadIdx.x;
  const int base = blockIdx.x * SCAN_CHUNK;
  int sum = 0;
#pragma unroll
  for (int j = 0; j < SCAN_VPT; ++j) {
    int i = base + tid + j * SCAN_BS;
    if (i < n) sum += cnt[i];
  }
#pragma unroll
  for (int off = 32; off > 0; off >>= 1) sum += __shfl_down(sum, off, 64);
  if ((tid & 63) == 0) s[tid >> 6] = sum;
  __syncthreads();
  if (tid == 0) {
    int t = 0;
#pragma unroll
    for (int w = 0; w < SCAN_BS / 64; ++w) t += s[w];
    partial[blockIdx.x] = t;
  }
}

__global__ __launch_bounds__(256) void k_scan_partials(int* __restrict__ partial, int p,
                                                       int* __restrict__ row_ptr, int n_nodes) {
  __shared__ int s[256];
  const int tid = threadIdx.x;
  int carry = 0;
  for (int base = 0; base < p; base += 256) {
    int i = base + tid;
    int v = (i < p) ? partial[i] : 0;
    s[tid] = v;
    __syncthreads();
    for (int off = 1; off < 256; off <<= 1) {
      int t = (tid >= off) ? s[tid - off] : 0;
      __syncthreads();
      s[tid] += t;
      __syncthreads();
    }
    if (i < p) partial[i] = carry + s[tid] - v;  // exclusive
    int tot = s[255];
    __syncthreads();
    carry += tot;
  }
  if (tid == 0) row_ptr[n_nodes] = carry;
}

__global__ __launch_bounds__(SCAN_BS) void k_scatter(const int* __restrict__ cnt,
                                                     const int* __restrict__ partial,
                                                     int* __restrict__ row_ptr,
                                                     float* __restrict__ inv, int n) {
  __shared__ int s[SCAN_BS];
  const int tid = threadIdx.x;
  const int base = blockIdx.x * SCAN_CHUNK;
  const int i0 = base + tid * SCAN_VPT;
  int v[SCAN_VPT];
  int cv[SCAN_VPT];
  int sum = 0;
#pragma unroll
  for (int j = 0; j < SCAN_VPT; ++j) {
    int i = i0 + j;
    int c = (i < n) ? cnt[i] : 0;
    cv[j] = c;
    v[j] = sum;
    sum += c;
  }
  s[tid] = sum;
  __syncthreads();
  for (int off = 1; off < SCAN_BS; off <<= 1) {
    int t = (tid >= off) ? s[tid - off] : 0;
    __syncthreads();
    s[tid] += t;
    __syncthreads();
  }
  const int excl = partial[blockIdx.x] + s[tid] - sum;
#pragma unroll
  for (int j = 0; j < SCAN_VPT; ++j) {
    int i = i0 + j;
    if (i < n) {
      row_ptr[i] = excl + v[j];
      inv[i] = 1.0f / (float)(cv[j] > 1 ? cv[j] : 1);
    }
  }
}

// place edges: csr16[row_ptr[dst] + rank] = (ushort)src ; no atomics
__global__ void k_place(const int* __restrict__ src, const int* __restrict__ dst,
                        const int* __restrict__ rank, const int* __restrict__ row_ptr,
                        ushort* __restrict__ csr16, int e) {
  int i0 = (blockIdx.x * blockDim.x + threadIdx.x) * 4;
  if (i0 >= e) return;
  if (i0 + 3 < e) {
    int4 dv = *(const int4*)(dst + i0);
    int4 sv = *(const int4*)(src + i0);
    int4 rv = *(const int4*)(rank + i0);
    int p0 = row_ptr[dv.x], p1 = row_ptr[dv.y], p2 = row_ptr[dv.z], p3 = row_ptr[dv.w];
    csr16[p0 + rv.x] = (ushort)sv.x;
    csr16[p1 + rv.y] = (ushort)sv.y;
    csr16[p2 + rv.z] = (ushort)sv.z;
    csr16[p3 + rv.w] = (ushort)sv.w;
  } else {
#pragma unroll
    for (int j = 0; j < 4; ++j) {
      int i = i0 + j;
      if (i < e) csr16[row_ptr[dst[i]] + rank[i]] = (ushort)src[i];
    }
  }
}

// -------- weight pack: split fp32 W into RNE-hi / RNE-residual-lo bf16 -------
// hi = rne(W) is the best standalone bf16 approx (layers 1/2 use hi only);
// hi + lo still reconstructs W to ~2^-18 rel (layer 0 uses both).
template <int FOUT>
__global__ void k_pack(const float* __restrict__ Wl, const float* __restrict__ Wr,
                       ushort* __restrict__ hi, ushort* __restrict__ lo) {
  constexpr int NCOL = 2 * FOUT;
  constexpr int NCHUNK = 4 * NCOL * 4;
  int ct = blockIdx.x * 256 + threadIdx.x;
  if (ct >= NCHUNK) return;
  const int g = ct & 3;
  const int nn = (ct >> 2) % NCOL;
  const int kt = ct / (4 * NCOL);
  uint hw[4], lw[4];
#pragma unroll
  for (int w = 0; w < 4; ++w) {
    uint h2[2], l2[2];
#pragma unroll
    for (int t = 0; t < 2; ++t) {
      int j = 2 * w + t;
      int k = kt * 32 + g * 8 + j;
      float v = (nn < FOUT) ? Wl[k * FOUT + nn] : Wr[k * FOUT + (nn - FOUT)];
      uint u = __float_as_uint(v);
      uint h = (u + 0x7FFFu + ((u >> 16) & 1u)) >> 16;   // RNE
      float r = v - __uint_as_float(h << 16);
      uint ur = __float_as_uint(r);
      uint l = (ur + 0x7FFFu + ((ur >> 16) & 1u)) >> 16; // RNE residual
      h2[t] = h; l2[t] = l;
    }
    hw[w] = h2[0] | (h2[1] << 16);
    lw[w] = l2[0] | (l2[1] << 16);
  }
  ((uint4*)hi)[ct] = make_uint4(hw[0], hw[1], hw[2], hw[3]);
  ((uint4*)lo)[ct] = make_uint4(lw[0], lw[1], lw[2], lw[3]);
}

// -------- layer-0 split-bf16 MFMA dual GEMM (A = fp32): Z(bf16), R(fp32)+b ----
template <int FOUT>
__global__ __launch_bounds__(256) void k_gemm2(const float* __restrict__ hin,
                                               const ushort* __restrict__ Whi,
                                               const ushort* __restrict__ Wlo,
                                               const float* __restrict__ bias,
                                               ushort* __restrict__ Zb,
                                               float* __restrict__ R, int n) {
  constexpr int NCOL = 2 * FOUT;
  constexpr int NT = NCOL / 64;  // n-tiles per wave
  constexpr int MT = 2;          // m-tiles (32 rows)
  __shared__ uint4 sA[2][32 * 16];  // [hi/lo][row][slot] 16B slots

  const int tid = threadIdx.x;
  const int lane = tid & 63;
  const int wave = tid >> 6;
  const int row0 = blockIdx.x * 32;

  // ---- stage 32x128 fp32 -> hi/lo bf16 in LDS ----
  {
    const int srow = tid >> 3;  // 0..31
    const int kc = tid & 7;     // 16-float chunk
    float4 f4[4];
    int g = row0 + srow;
    if (g < n) {
      const float4* hp = (const float4*)(hin + (size_t)g * 128 + kc * 16);
      f4[0] = hp[0]; f4[1] = hp[1]; f4[2] = hp[2]; f4[3] = hp[3];
    } else {
      f4[0] = f4[1] = f4[2] = f4[3] = make_float4(0.f, 0.f, 0.f, 0.f);
    }
    const float* fp = (const float*)f4;
#pragma unroll
    for (int b = 0; b < 2; ++b) {
      uint hw[4], lw[4];
#pragma unroll
      for (int w = 0; w < 4; ++w) {
        float a0 = fp[b * 8 + 2 * w], a1 = fp[b * 8 + 2 * w + 1];
        uint u0 = __float_as_uint(a0), u1 = __float_as_uint(a1);
        uint h0 = u0 >> 16, h1 = u1 >> 16;
        float r0 = a0 - __uint_as_float(h0 << 16);
        float r1 = a1 - __uint_as_float(h1 << 16);
        uint l0 = __float_as_uint(r0) >> 16, l1 = __float_as_uint(r1) >> 16;
        hw[w] = h0 | (h1 << 16);
        lw[w] = l0 | (l1 << 16);
      }
      int slot = (kc * 2 + b) ^ (srow & 7);
      sA[0][srow * 16 + slot] = make_uint4(hw[0], hw[1], hw[2], hw[3]);
      sA[1][srow * 16 + slot] = make_uint4(lw[0], lw[1], lw[2], lw[3]);
    }
  }
  __syncthreads();

  const int n0 = wave * (NCOL / 4);
  const int g16 = lane >> 4;   // k-group 0..3
  const int l16 = lane & 15;

  f32x4 acc[MT][NT];
#pragma unroll
  for (int mt = 0; mt < MT; ++mt)
#pragma unroll
    for (int nt = 0; nt < NT; ++nt) acc[mt][nt] = (f32x4)(0.f);

#pragma unroll
  for (int kt = 0; kt < 4; ++kt) {
    short8 ahi[MT], alo[MT];
#pragma unroll
    for (int mt = 0; mt < MT; ++mt) {
      int row = mt * 16 + l16;
      int slot = (kt * 4 + g16) ^ (row & 7);
      ahi[mt] = *(const short8*)&sA[0][row * 16 + slot];
      alo[mt] = *(const short8*)&sA[1][row * 16 + slot];
    }
    short8 bh[NT];
#pragma unroll
    for (int nt = 0; nt < NT; ++nt) {
      size_t chunk = (size_t)(kt * NCOL + n0 + nt * 16 + l16) * 4 + g16;
      bh[nt] = *(const short8*)(Whi + chunk * 8);
    }
#pragma unroll
    for (int mt = 0; mt < MT; ++mt)
#pragma unroll
      for (int nt = 0; nt < NT; ++nt)
        acc[mt][nt] = __builtin_amdgcn_mfma_f32_16x16x32_bf16(ahi[mt], bh[nt], acc[mt][nt], 0, 0, 0);
#pragma unroll
    for (int mt = 0; mt < MT; ++mt)
#pragma unroll
      for (int nt = 0; nt < NT; ++nt)
        acc[mt][nt] = __builtin_amdgcn_mfma_f32_16x16x32_bf16(alo[mt], bh[nt], acc[mt][nt], 0, 0, 0);
    short8 bl[NT];
#pragma unroll
    for (int nt = 0; nt < NT; ++nt) {
      size_t chunk = (size_t)(kt * NCOL + n0 + nt * 16 + l16) * 4 + g16;
      bl[nt] = *(const short8*)(Wlo + chunk * 8);
    }
#pragma unroll
    for (int mt = 0; mt < MT; ++mt)
#pragma unroll
      for (int nt = 0; nt < NT; ++nt)
        acc[mt][nt] = __builtin_amdgcn_mfma_f32_16x16x32_bf16(ahi[mt], bl[nt], acc[mt][nt], 0, 0, 0);
  }

  // ---- epilogue: C/D layout col=lane&15, row=(lane>>4)*4+j ----
#pragma unroll
  for (int nt = 0; nt < NT; ++nt) {
    int col = n0 + nt * 16 + l16;
    bool isR = col >= FOUT;
    int cw = isR ? col - FOUT : col;
    float badd = isR ? bias[cw] : 0.f;
#pragma unroll
    for (int mt = 0; mt < MT; ++mt) {
#pragma unroll
      for (int j = 0; j < 4; ++j) {
        int row = row0 + mt * 16 + g16 * 4 + j;
        if (row < n) {
          float v = acc[mt][nt][j] + badd;
          if (isR) R[(size_t)row * FOUT + cw] = v;
          else Zb[(size_t)row * FOUT + cw] = bf16_rne(v);
        }
      }
    }
  }
}

// -------- layers 1/2: A bf16 x W_hi bf16 (RNE), LDS-staged, 32 rows (MT=2) ---
// R11 lesson: MT=4 starved TLP (3 blocks/CU). Instead cut the latency chain:
// single W chain (A is already bf16-rounded, lo adds no usable precision),
// halving weight loads and MFMAs per kt.
template <int FOUT>
__global__ __launch_bounds__(256) void k_gemm2b(const ushort* __restrict__ Hb,
                                                const ushort* __restrict__ Whi,
                                                const float* __restrict__ bias,
                                                ushort* __restrict__ Zb,
                                                float* __restrict__ R, int n) {
  constexpr int NCOL = 2 * FOUT;
  constexpr int NT = NCOL / 64;
  constexpr int MT = 2;
  __shared__ uint4 sA[32 * 16];  // 8KB: 32 rows x 16 slots of 16B

  const int tid = threadIdx.x;
  const int lane = tid & 63;
  const int wave = tid >> 6;
  const int row0 = blockIdx.x * 32;

#pragma unroll
  for (int c = tid; c < 512; c += 256) {
    int srow = c >> 4, col16 = c & 15;
    int g = row0 + srow;
    uint4 v = make_uint4(0u, 0u, 0u, 0u);
    if (g < n) v = *(const uint4*)(Hb + (size_t)g * 128 + col16 * 8);
    sA[srow * 16 + (col16 ^ (srow & 7))] = v;
  }
  __syncthreads();

  const int n0 = wave * (NCOL / 4);
  const int g16 = lane >> 4;
  const int l16 = lane & 15;

  f32x4 acc[MT][NT];
#pragma unroll
  for (int mt = 0; mt < MT; ++mt)
#pragma unroll
    for (int nt = 0; nt < NT; ++nt) acc[mt][nt] = (f32x4)(0.f);

#pragma unroll
  for (int kt = 0; kt < 4; ++kt) {
    short8 a[MT];
#pragma unroll
    for (int mt = 0; mt < MT; ++mt) {
      int row = mt * 16 + l16;
      int slot = (kt * 4 + g16) ^ (row & 7);
      a[mt] = *(const short8*)&sA[row * 16 + slot];
    }
    short8 bh[NT];
#pragma unroll
    for (int nt = 0; nt < NT; ++nt) {
      size_t chunk = (size_t)(kt * NCOL + n0 + nt * 16 + l16) * 4 + g16;
      bh[nt] = *(const short8*)(Whi + chunk * 8);
    }
#pragma unroll
    for (int mt = 0; mt < MT; ++mt)
#pragma unroll
      for (int nt = 0; nt < NT; ++nt)
        acc[mt][nt] = __builtin_amdgcn_mfma_f32_16x16x32_bf16(a[mt], bh[nt], acc[mt][nt], 0, 0, 0);
  }

#pragma unroll
  for (int nt = 0; nt < NT; ++nt) {
    int col = n0 + nt * 16 + l16;
    bool isR = col >= FOUT;
    int cw = isR ? col - FOUT : col;
    float badd = isR ? bias[cw] : 0.f;
#pragma unroll
    for (int mt = 0; mt < MT; ++mt) {
#pragma unroll
      for (int j = 0; j < 4; ++j) {
        int row = row0 + mt * 16 + g16 * 4 + j;
        if (row < n) {
          float v = acc[mt][nt][j] + badd;
          if (isR) R[(size_t)row * FOUT + cw] = v;
          else Zb[(size_t)row * FOUT + cw] = bf16_rne(v);
        }
      }
    }
  }
}

// -------- CSR mean-aggregation + epilogue: out = act(mean(Zb)*inv + R) --------
// OUTB: write bf16 H (16B/lane) for middle layers; fp32 for the final output.
template <int FOUT, bool RELU, bool OUTB>
__global__ __launch_bounds__(256) void k_agg2(const ushort* __restrict__ Zb,
                                              const float* __restrict__ R,
                                              const int* __restrict__ row_ptr,
                                              const ushort* __restrict__ csr16,
                                              const float* __restrict__ inv,
                                              void* __restrict__ outp, int n) {
  constexpr int FL = FOUT / 8;  // lanes per row (16 or 8)
  constexpr int EG = 64 / FL;   // edge groups per wave (4 or 8)
  const int lane = threadIdx.x & 63;
  const int node = blockIdx.x * 4 + (threadIdx.x >> 6);
  if (node >= n) return;
  const int c = lane % FL;
  const int eg = lane / FL;

  const int e0 = row_ptr[node];
  const int m = row_ptr[node + 1] - e0;  // wave-uniform
  const uint4* Z4 = (const uint4*)Zb;    // 16B = 8 bf16

  float acc[8];
#pragma unroll
  for (int k = 0; k < 8; ++k) acc[k] = 0.f;

  int t = eg;
  while (t < m) {
    int ss[4];
#pragma unroll
    for (int j = 0; j < 4; ++j) {
      int tj = t + j * EG;
      int tc = (tj < m) ? tj : (m - 1);  // clamped: always valid
      ss[j] = csr16[e0 + tc];
    }
    uint4 z[4];
#pragma unroll
    for (int j = 0; j < 4; ++j) z[j] = Z4[(size_t)ss[j] * FL + c];
#pragma unroll
    for (int j = 0; j < 4; ++j) {
      if (t + j * EG < m) {
        const uint* zw = (const uint*)&z[j];
#pragma unroll
        for (int w = 0; w < 4; ++w) {
          acc[2 * w]     += __uint_as_float(zw[w] << 16);
          acc[2 * w + 1] += __uint_as_float(zw[w] & 0xFFFF0000u);
        }
      }
    }
    t += 4 * EG;
  }

#pragma unroll
  for (int off = FL; off < 64; off <<= 1) {
#pragma unroll
    for (int k = 0; k < 8; ++k) acc[k] += __shfl_xor(acc[k], off, 64);
  }

  if (eg == 0) {
    const float iv = inv[node];
    const float4* Rp = (const float4*)(R + (size_t)node * FOUT + c * 8);
    float4 r0 = Rp[0], r1 = Rp[1];
    float o[8];
    o[0] = fmaf(acc[0], iv, r0.x);
    o[1] = fmaf(acc[1], iv, r0.y);
    o[2] = fmaf(acc[2], iv, r0.z);
    o[3] = fmaf(acc[3], iv, r0.w);
    o[4] = fmaf(acc[4], iv, r1.x);
    o[5] = fmaf(acc[5], iv, r1.y);
    o[6] = fmaf(acc[6], iv, r1.z);
    o[7] = fmaf(acc[7], iv, r1.w);
    if (RELU) {
#pragma unroll
      for (int k = 0; k < 8; ++k) o[k] = fmaxf(o[k], 0.f);
    }
    if (OUTB) {
      uint p[4];
#pragma unroll
      for (int w = 0; w < 4; ++w)
        p[w] = (uint)bf16_rne(o[2 * w]) | ((uint)bf16_rne(o[2 * w + 1]) << 16);
      ((uint4*)outp)[(size_t)node * FL + c] = make_uint4(p[0], p[1], p[2], p[3]);
    } else {
      float4* op = (float4*)((float*)outp + (size_t)node * FOUT + c * 8);
      op[0] = make_float4(o[0], o[1], o[2], o[3]);
      op[1] = make_float4(o[4], o[5], o[6], o[7]);
    }
  }
}

// ---------------- launch ----------------

extern "C" void kernel_launch(void* const* d_in, const int* in_sizes, int n_in,
                              void* d_out, int out_size, void* d_ws, size_t ws_size,
                              hipStream_t stream) {
  const float* x   = (const float*)d_in[0];
  const int*   ei  = (const int*)d_in[1];
  const float* Wl0 = (const float*)d_in[2];
  const float* bl0 = (const float*)d_in[3];
  const float* Wr0 = (const float*)d_in[4];
  const float* Wl1 = (const float*)d_in[5];
  const float* bl1 = (const float*)d_in[6];
  const float* Wr1 = (const float*)d_in[7];
  const float* Wl2 = (const float*)d_in[8];
  const float* bl2 = (const float*)d_in[9];
  const float* Wr2 = (const float*)d_in[10];
  float* out = (float*)d_out;

  const int N = in_sizes[0] / 128;
  const int E = in_sizes[1] / 2;
  const int* src = ei;
  const int* dst = ei + E;

  char* w = (char*)d_ws;
  auto alloc = [&](size_t bytes) {
    char* p = w;
    w += (bytes + 255) & ~(size_t)255;
    return p;
  };
  int*    cnt     = (int*)alloc((size_t)N * 4);
  int*    row_ptr = (int*)alloc((size_t)(N + 1) * 4);
  int*    rank    = (int*)alloc((size_t)E * 4);
  ushort* csr16   = (ushort*)alloc((size_t)E * 2 + 256);
  float*  inv     = (float*)alloc((size_t)N * 4);
  int*    partial = (int*)alloc((size_t)ceil_div(N, SCAN_CHUNK) * 4 + 256);
  ushort* Whi0    = (ushort*)alloc((size_t)4 * 256 * 4 * 16);
  ushort* Wlo0    = (ushort*)alloc((size_t)4 * 256 * 4 * 16);
  ushort* Whi1    = (ushort*)alloc((size_t)4 * 256 * 4 * 16);
  ushort* Wlo1    = (ushort*)alloc((size_t)4 * 256 * 4 * 16);
  ushort* Whi2    = (ushort*)alloc((size_t)4 * 128 * 4 * 16);
  ushort* Wlo2    = (ushort*)alloc((size_t)4 * 128 * 4 * 16);
  ushort* BZ      = (ushort*)alloc((size_t)N * 128 * 2);
  float*  BR      = (float*)alloc((size_t)N * 128 * 4);
  ushort* B0      = (ushort*)alloc((size_t)N * 128 * 2);  // H in bf16
  (void)ws_size; (void)n_in; (void)out_size;

  const int P = ceil_div(N, SCAN_CHUNK);

  // ---- weight packs ----
  k_pack<128><<<16, 256, 0, stream>>>(Wl0, Wr0, Whi0, Wlo0);
  k_pack<128><<<16, 256, 0, stream>>>(Wl1, Wr1, Whi1, Wlo1);
  k_pack<64><<<8, 256, 0, stream>>>(Wl2, Wr2, Whi2, Wlo2);

  // ---- CSR build (rank-based, single atomic pass) ----
  k_zero_int<<<ceil_div(N, 256), 256, 0, stream>>>(cnt, N);
  k_count_rank<<<ceil_div(E, 1024), 256, 0, stream>>>(dst, cnt, rank, E);
  k_blocksum<<<P, SCAN_BS, 0, stream>>>(cnt, partial, N);
  k_scan_partials<<<1, 256, 0, stream>>>(partial, P, row_ptr, N);
  k_scatter<<<P, SCAN_BS, 0, stream>>>(cnt, partial, row_ptr, inv, N);
  k_place<<<ceil_div(E, 1024), 256, 0, stream>>>(src, dst, rank, row_ptr, csr16, E);

  // ---- layer 0: x (fp32) -> (Zb,R) -> H1 bf16 (B0) ----
  k_gemm2<128><<<ceil_div(N, 32), 256, 0, stream>>>(x, Whi0, Wlo0, bl0, BZ, BR, N);
  k_agg2<128, true, true><<<ceil_div(N, 4), 256, 0, stream>>>(BZ, BR, row_ptr, csr16, inv, B0, N);

  // ---- layer 1: H1 bf16 -> (Zb,R) -> H2 bf16 (B0) ----
  k_gemm2b<128><<<ceil_div(N, 32), 256, 0, stream>>>(B0, Whi1, bl1, BZ, BR, N);
  k_agg2<128, true, true><<<ceil_div(N, 4), 256, 0, stream>>>(BZ, BR, row_ptr, csr16, inv, B0, N);

  // ---- layer 2: H2 bf16 -> (Zb,R) 64-wide -> out fp32 ----
  k_gemm2b<64><<<ceil_div(N, 32), 256, 0, stream>>>(B0, Whi2, bl2, BZ, BR, N);
  k_agg2<64, false, false><<<ceil_div(N, 4), 256, 0, stream>>>(BZ, BR, row_ptr, csr16, inv, out, N);
}

// Round 13
// 223.414 us; speedup vs baseline: 1.0780x; 1.0057x over previous
//
#include <hip/hip_runtime.h>

static inline int ceil_div(int a, int b) { return (a + b - 1) / b; }

typedef __attribute__((ext_vector_type(8))) short short8;   // 8 bf16 = 4 VGPR
typedef __attribute__((ext_vector_type(4))) float f32x4;

__device__ __forceinline__ ushort bf16_rne(float v) {
  uint u = __float_as_uint(v);
  return (ushort)((u + 0x7FFFu + ((u >> 16) & 1u)) >> 16);
}

// ---------------- misc ----------------

__global__ void k_zero_int(int* __restrict__ p, int n) {
  int i = blockIdx.x * blockDim.x + threadIdx.x;
  if (i < n) p[i] = 0;
}

// fp32 -> bf16 (RNE) streaming convert, 8 elems/thread
__global__ void k_cvt(const float* __restrict__ in, ushort* __restrict__ outp, int n8) {
  int i = blockIdx.x * blockDim.x + threadIdx.x;
  if (i >= n8) return;
  const float4* ip = (const float4*)(in + (size_t)i * 8);
  float4 a = ip[0], b = ip[1];
  uint p0 = (uint)bf16_rne(a.x) | ((uint)bf16_rne(a.y) << 16);
  uint p1 = (uint)bf16_rne(a.z) | ((uint)bf16_rne(a.w) << 16);
  uint p2 = (uint)bf16_rne(b.x) | ((uint)bf16_rne(b.y) << 16);
  uint p3 = (uint)bf16_rne(b.z) | ((uint)bf16_rne(b.w) << 16);
  ((uint4*)outp)[i] = make_uint4(p0, p1, p2, p3);
}

// ---------------- CSR build ----------------

// histogram + per-edge rank (ushort ranks; 4 atomics in flight)
__global__ void k_count_rank(const int* __restrict__ dst, int* __restrict__ cnt,
                             ushort* __restrict__ rank, int e) {
  int i0 = (blockIdx.x * blockDim.x + threadIdx.x) * 4;
  if (i0 >= e) return;
  int d[4], r[4];
  if (i0 + 3 < e) {
    int4 dv = *(const int4*)(dst + i0);
    d[0] = dv.x; d[1] = dv.y; d[2] = dv.z; d[3] = dv.w;
  } else {
#pragma unroll
    for (int j = 0; j < 4; ++j) d[j] = (i0 + j < e) ? dst[i0 + j] : 0;
  }
#pragma unroll
  for (int j = 0; j < 4; ++j)
    if (i0 + j < e) r[j] = atomicAdd(&cnt[d[j]], 1);
  if (i0 + 3 < e) {
    ushort4 rv;
    rv.x = (ushort)r[0]; rv.y = (ushort)r[1];
    rv.z = (ushort)r[2]; rv.w = (ushort)r[3];
    *(ushort4*)(rank + i0) = rv;
  } else {
#pragma unroll
    for (int j = 0; j < 4; ++j)
      if (i0 + j < e) rank[i0 + j] = (ushort)r[j];
  }
}

#define SCAN_BS 256
#define SCAN_VPT 4
#define SCAN_CHUNK (SCAN_BS * SCAN_VPT)

__global__ __launch_bounds__(SCAN_BS) void k_blocksum(const int* __restrict__ cnt,
                                                      int* __restrict__ partial, int n) {
  __shared__ int s[SCAN_BS / 64];
  const int tid = threadIdx.x;
  const int base = blockIdx.x * SCAN_CHUNK;
  int sum = 0;
#pragma unroll
  for (int j = 0; j < SCAN_VPT; ++j) {
    int i = base + tid + j * SCAN_BS;
    if (i < n) sum += cnt[i];
  }
#pragma unroll
  for (int off = 32; off > 0; off >>= 1) sum += __shfl_down(sum, off, 64);
  if ((tid & 63) == 0) s[tid >> 6] = sum;
  __syncthreads();
  if (tid == 0) {
    int t = 0;
#pragma unroll
    for (int w = 0; w < SCAN_BS / 64; ++w) t += s[w];
    partial[blockIdx.x] = t;
  }
}

__global__ __launch_bounds__(256) void k_scan_partials(int* __restrict__ partial, int p,
                                                       int* __restrict__ row_ptr, int n_nodes) {
  __shared__ int s[256];
  const int tid = threadIdx.x;
  int carry = 0;
  for (int base = 0; base < p; base += 256) {
    int i = base + tid;
    int v = (i < p) ? partial[i] : 0;
    s[tid] = v;
    __syncthreads();
    for (int off = 1; off < 256; off <<= 1) {
      int t = (tid >= off) ? s[tid - off] : 0;
      __syncthreads();
      s[tid] += t;
      __syncthreads();
    }
    if (i < p) partial[i] = carry + s[tid] - v;  // exclusive
    int tot = s[255];
    __syncthreads();
    carry += tot;
  }
  if (tid == 0) row_ptr[n_nodes] = carry;
}

__global__ __launch_bounds__(SCAN_BS) void k_scatter(const int* __restrict__ cnt,
                                                     const int* __restrict__ partial,
                                                     int* __restrict__ row_ptr,
                                                     float* __restrict__ inv, int n) {
  __shared__ int s[SCAN_BS];
  const int tid = threadIdx.x;
  const int base = blockIdx.x * SCAN_CHUNK;
  const int i0 = base + tid * SCAN_VPT;
  int v[SCAN_VPT];
  int cv[SCAN_VPT];
  int sum = 0;
#pragma unroll
  for (int j = 0; j < SCAN_VPT; ++j) {
    int i = i0 + j;
    int c = (i < n) ? cnt[i] : 0;
    cv[j] = c;
    v[j] = sum;
    sum += c;
  }
  s[tid] = sum;
  __syncthreads();
  for (int off = 1; off < SCAN_BS; off <<= 1) {
    int t = (tid >= off) ? s[tid - off] : 0;
    __syncthreads();
    s[tid] += t;
    __syncthreads();
  }
  const int excl = partial[blockIdx.x] + s[tid] - sum;
#pragma unroll
  for (int j = 0; j < SCAN_VPT; ++j) {
    int i = i0 + j;
    if (i < n) {
      row_ptr[i] = excl + v[j];
      inv[i] = 1.0f / (float)(cv[j] > 1 ? cv[j] : 1);
    }
  }
}

// place edges: csr16[row_ptr[dst] + rank] = (ushort)src ; no atomics
__global__ void k_place(const int* __restrict__ src, const int* __restrict__ dst,
                        const ushort* __restrict__ rank, const int* __restrict__ row_ptr,
                        ushort* __restrict__ csr16, int e) {
  int i0 = (blockIdx.x * blockDim.x + threadIdx.x) * 4;
  if (i0 >= e) return;
  if (i0 + 3 < e) {
    int4 dv = *(const int4*)(dst + i0);
    int4 sv = *(const int4*)(src + i0);
    ushort4 rv = *(const ushort4*)(rank + i0);
    int p0 = row_ptr[dv.x], p1 = row_ptr[dv.y], p2 = row_ptr[dv.z], p3 = row_ptr[dv.w];
    csr16[p0 + rv.x] = (ushort)sv.x;
    csr16[p1 + rv.y] = (ushort)sv.y;
    csr16[p2 + rv.z] = (ushort)sv.z;
    csr16[p3 + rv.w] = (ushort)sv.w;
  } else {
#pragma unroll
    for (int j = 0; j < 4; ++j) {
      int i = i0 + j;
      if (i < e) csr16[row_ptr[dst[i]] + rank[i]] = (ushort)src[i];
    }
  }
}

// -------- weight pack: fp32 W -> RNE bf16, MFMA-B-fragment order -------------
template <int FOUT>
__global__ void k_pack(const float* __restrict__ Wl, const float* __restrict__ Wr,
                       ushort* __restrict__ hi) {
  constexpr int NCOL = 2 * FOUT;
  constexpr int NCHUNK = 4 * NCOL * 4;
  int ct = blockIdx.x * 256 + threadIdx.x;
  if (ct >= NCHUNK) return;
  const int g = ct & 3;
  const int nn = (ct >> 2) % NCOL;
  const int kt = ct / (4 * NCOL);
  uint hw[4];
#pragma unroll
  for (int w = 0; w < 4; ++w) {
    uint h2[2];
#pragma unroll
    for (int t = 0; t < 2; ++t) {
      int j = 2 * w + t;
      int k = kt * 32 + g * 8 + j;
      float v = (nn < FOUT) ? Wl[k * FOUT + nn] : Wr[k * FOUT + (nn - FOUT)];
      h2[t] = (uint)bf16_rne(v);
    }
    hw[w] = h2[0] | (h2[1] << 16);
  }
  ((uint4*)hi)[ct] = make_uint4(hw[0], hw[1], hw[2], hw[3]);
}

// -------- all layers: A bf16 x W bf16 (RNE), LDS-staged dual GEMM, MT=2 ------
// Z(bf16) = A@Wl ; R(fp32) = A@Wr + b
template <int FOUT>
__global__ __launch_bounds__(256) void k_gemm2b(const ushort* __restrict__ Hb,
                                                const ushort* __restrict__ Whi,
                                                const float* __restrict__ bias,
                                                ushort* __restrict__ Zb,
                                                float* __restrict__ R, int n) {
  constexpr int NCOL = 2 * FOUT;
  constexpr int NT = NCOL / 64;
  constexpr int MT = 2;
  __shared__ uint4 sA[32 * 16];  // 8KB: 32 rows x 16 slots of 16B

  const int tid = threadIdx.x;
  const int lane = tid & 63;
  const int wave = tid >> 6;
  const int row0 = blockIdx.x * 32;

#pragma unroll
  for (int c = tid; c < 512; c += 256) {
    int srow = c >> 4, col16 = c & 15;
    int g = row0 + srow;
    uint4 v = make_uint4(0u, 0u, 0u, 0u);
    if (g < n) v = *(const uint4*)(Hb + (size_t)g * 128 + col16 * 8);
    sA[srow * 16 + (col16 ^ (srow & 7))] = v;
  }
  __syncthreads();

  const int n0 = wave * (NCOL / 4);
  const int g16 = lane >> 4;
  const int l16 = lane & 15;

  f32x4 acc[MT][NT];
#pragma unroll
  for (int mt = 0; mt < MT; ++mt)
#pragma unroll
    for (int nt = 0; nt < NT; ++nt) acc[mt][nt] = (f32x4)(0.f);

#pragma unroll
  for (int kt = 0; kt < 4; ++kt) {
    short8 a[MT];
#pragma unroll
    for (int mt = 0; mt < MT; ++mt) {
      int row = mt * 16 + l16;
      int slot = (kt * 4 + g16) ^ (row & 7);
      a[mt] = *(const short8*)&sA[row * 16 + slot];
    }
    short8 bh[NT];
#pragma unroll
    for (int nt = 0; nt < NT; ++nt) {
      size_t chunk = (size_t)(kt * NCOL + n0 + nt * 16 + l16) * 4 + g16;
      bh[nt] = *(const short8*)(Whi + chunk * 8);
    }
#pragma unroll
    for (int mt = 0; mt < MT; ++mt)
#pragma unroll
      for (int nt = 0; nt < NT; ++nt)
        acc[mt][nt] = __builtin_amdgcn_mfma_f32_16x16x32_bf16(a[mt], bh[nt], acc[mt][nt], 0, 0, 0);
  }

#pragma unroll
  for (int nt = 0; nt < NT; ++nt) {
    int col = n0 + nt * 16 + l16;
    bool isR = col >= FOUT;
    int cw = isR ? col - FOUT : col;
    float badd = isR ? bias[cw] : 0.f;
#pragma unroll
    for (int mt = 0; mt < MT; ++mt) {
#pragma unroll
      for (int j = 0; j < 4; ++j) {
        int row = row0 + mt * 16 + g16 * 4 + j;
        if (row < n) {
          float v = acc[mt][nt][j] + badd;
          if (isR) R[(size_t)row * FOUT + cw] = v;
          else Zb[(size_t)row * FOUT + cw] = bf16_rne(v);
        }
      }
    }
  }
}

// -------- CSR mean-aggregation + epilogue: out = act(mean(Zb)*inv + R) --------
// OUTB: write bf16 H (16B/lane) for middle layers; fp32 for the final output.
template <int FOUT, bool RELU, bool OUTB>
__global__ __launch_bounds__(256) void k_agg2(const ushort* __restrict__ Zb,
                                              const float* __restrict__ R,
                                              const int* __restrict__ row_ptr,
                                              const ushort* __restrict__ csr16,
                                              const float* __restrict__ inv,
                                              void* __restrict__ outp, int n) {
  constexpr int FL = FOUT / 8;  // lanes per row (16 or 8)
  constexpr int EG = 64 / FL;   // edge groups per wave (4 or 8)
  const int lane = threadIdx.x & 63;
  const int node = blockIdx.x * 4 + (threadIdx.x >> 6);
  if (node >= n) return;
  const int c = lane % FL;
  const int eg = lane / FL;

  const int e0 = row_ptr[node];
  const int m = row_ptr[node + 1] - e0;  // wave-uniform
  const uint4* Z4 = (const uint4*)Zb;    // 16B = 8 bf16

  float acc[8];
#pragma unroll
  for (int k = 0; k < 8; ++k) acc[k] = 0.f;

  int t = eg;
  while (t < m) {
    int ss[4];
#pragma unroll
    for (int j = 0; j < 4; ++j) {
      int tj = t + j * EG;
      int tc = (tj < m) ? tj : (m - 1);  // clamped: always valid
      ss[j] = csr16[e0 + tc];
    }
    uint4 z[4];
#pragma unroll
    for (int j = 0; j < 4; ++j) z[j] = Z4[(size_t)ss[j] * FL + c];
#pragma unroll
    for (int j = 0; j < 4; ++j) {
      if (t + j * EG < m) {
        const uint* zw = (const uint*)&z[j];
#pragma unroll
        for (int w = 0; w < 4; ++w) {
          acc[2 * w]     += __uint_as_float(zw[w] << 16);
          acc[2 * w + 1] += __uint_as_float(zw[w] & 0xFFFF0000u);
        }
      }
    }
    t += 4 * EG;
  }

#pragma unroll
  for (int off = FL; off < 64; off <<= 1) {
#pragma unroll
    for (int k = 0; k < 8; ++k) acc[k] += __shfl_xor(acc[k], off, 64);
  }

  if (eg == 0) {
    const float iv = inv[node];
    const float4* Rp = (const float4*)(R + (size_t)node * FOUT + c * 8);
    float4 r0 = Rp[0], r1 = Rp[1];
    float o[8];
    o[0] = fmaf(acc[0], iv, r0.x);
    o[1] = fmaf(acc[1], iv, r0.y);
    o[2] = fmaf(acc[2], iv, r0.z);
    o[3] = fmaf(acc[3], iv, r0.w);
    o[4] = fmaf(acc[4], iv, r1.x);
    o[5] = fmaf(acc[5], iv, r1.y);
    o[6] = fmaf(acc[6], iv, r1.z);
    o[7] = fmaf(acc[7], iv, r1.w);
    if (RELU) {
#pragma unroll
      for (int k = 0; k < 8; ++k) o[k] = fmaxf(o[k], 0.f);
    }
    if (OUTB) {
      uint p[4];
#pragma unroll
      for (int w = 0; w < 4; ++w)
        p[w] = (uint)bf16_rne(o[2 * w]) | ((uint)bf16_rne(o[2 * w + 1]) << 16);
      ((uint4*)outp)[(size_t)node * FL + c] = make_uint4(p[0], p[1], p[2], p[3]);
    } else {
      float4* op = (float4*)((float*)outp + (size_t)node * FOUT + c * 8);
      op[0] = make_float4(o[0], o[1], o[2], o[3]);
      op[1] = make_float4(o[4], o[5], o[6], o[7]);
    }
  }
}

// ---------------- launch ----------------

extern "C" void kernel_launch(void* const* d_in, const int* in_sizes, int n_in,
                              void* d_out, int out_size, void* d_ws, size_t ws_size,
                              hipStream_t stream) {
  const float* x   = (const float*)d_in[0];
  const int*   ei  = (const int*)d_in[1];
  const float* Wl0 = (const float*)d_in[2];
  const float* bl0 = (const float*)d_in[3];
  const float* Wr0 = (const float*)d_in[4];
  const float* Wl1 = (const float*)d_in[5];
  const float* bl1 = (const float*)d_in[6];
  const float* Wr1 = (const float*)d_in[7];
  const float* Wl2 = (const float*)d_in[8];
  const float* bl2 = (const float*)d_in[9];
  const float* Wr2 = (const float*)d_in[10];
  float* out = (float*)d_out;

  const int N = in_sizes[0] / 128;
  const int E = in_sizes[1] / 2;
  const int* src = ei;
  const int* dst = ei + E;

  char* w = (char*)d_ws;
  auto alloc = [&](size_t bytes) {
    char* p = w;
    w += (bytes + 255) & ~(size_t)255;
    return p;
  };
  int*    cnt     = (int*)alloc((size_t)N * 4);
  int*    row_ptr = (int*)alloc((size_t)(N + 1) * 4);
  ushort* rank    = (ushort*)alloc((size_t)E * 2 + 256);
  ushort* csr16   = (ushort*)alloc((size_t)E * 2 + 256);
  float*  inv     = (float*)alloc((size_t)N * 4);
  int*    partial = (int*)alloc((size_t)ceil_div(N, SCAN_CHUNK) * 4 + 256);
  ushort* Whi0    = (ushort*)alloc((size_t)4 * 256 * 4 * 16);
  ushort* Whi1    = (ushort*)alloc((size_t)4 * 256 * 4 * 16);
  ushort* Whi2    = (ushort*)alloc((size_t)4 * 128 * 4 * 16);
  ushort* XB      = (ushort*)alloc((size_t)N * 128 * 2);  // x in bf16
  ushort* BZ      = (ushort*)alloc((size_t)N * 128 * 2);
  float*  BR      = (float*)alloc((size_t)N * 128 * 4);
  ushort* B0      = (ushort*)alloc((size_t)N * 128 * 2);  // H in bf16
  (void)ws_size; (void)n_in; (void)out_size;

  const int P = ceil_div(N, SCAN_CHUNK);

  // ---- weight packs + x convert ----
  k_pack<128><<<16, 256, 0, stream>>>(Wl0, Wr0, Whi0);
  k_pack<128><<<16, 256, 0, stream>>>(Wl1, Wr1, Whi1);
  k_pack<64><<<8, 256, 0, stream>>>(Wl2, Wr2, Whi2);
  k_cvt<<<ceil_div(N * 16, 256), 256, 0, stream>>>(x, XB, N * 16);

  // ---- CSR build (rank-based, single atomic pass) ----
  k_zero_int<<<ceil_div(N, 256), 256, 0, stream>>>(cnt, N);
  k_count_rank<<<ceil_div(E, 1024), 256, 0, stream>>>(dst, cnt, rank, E);
  k_blocksum<<<P, SCAN_BS, 0, stream>>>(cnt, partial, N);
  k_scan_partials<<<1, 256, 0, stream>>>(partial, P, row_ptr, N);
  k_scatter<<<P, SCAN_BS, 0, stream>>>(cnt, partial, row_ptr, inv, N);
  k_place<<<ceil_div(E, 1024), 256, 0, stream>>>(src, dst, rank, row_ptr, csr16, E);

  // ---- layer 0: xb -> (Zb,R) -> H1 bf16 (B0) ----
  k_gemm2b<128><<<ceil_div(N, 32), 256, 0, stream>>>(XB, Whi0, bl0, BZ, BR, N);
  k_agg2<128, true, true><<<ceil_div(N, 4), 256, 0, stream>>>(BZ, BR, row_ptr, csr16, inv, B0, N);

  // ---- layer 1: H1 bf16 -> (Zb,R) -> H2 bf16 (B0) ----
  k_gemm2b<128><<<ceil_div(N, 32), 256, 0, stream>>>(B0, Whi1, bl1, BZ, BR, N);
  k_agg2<128, true, true><<<ceil_div(N, 4), 256, 0, stream>>>(BZ, BR, row_ptr, csr16, inv, B0, N);

  // ---- layer 2: H2 bf16 -> (Zb,R) 64-wide -> out fp32 ----
  k_gemm2b<64><<<ceil_div(N, 32), 256, 0, stream>>>(B0, Whi2, bl2, BZ, BR, N);
  k_agg2<64, false, false><<<ceil_div(N, 4), 256, 0, stream>>>(BZ, BR, row_ptr, csr16, inv, out, N);
}

// Round 14
// 220.775 us; speedup vs baseline: 1.0908x; 1.0120x over previous
//
#include <hip/hip_runtime.h>

static inline int ceil_div(int a, int b) { return (a + b - 1) / b; }

typedef __attribute__((ext_vector_type(8))) short short8;   // 8 bf16 = 4 VGPR
typedef __attribute__((ext_vector_type(4))) float f32x4;

__device__ __forceinline__ ushort bf16_rne(float v) {
  uint u = __float_as_uint(v);
  return (ushort)((u + 0x7FFFu + ((u >> 16) & 1u)) >> 16);
}

// ---------------- misc ----------------

__global__ void k_zero_int(int* __restrict__ p, int n) {
  int i = blockIdx.x * blockDim.x + threadIdx.x;
  if (i < n) p[i] = 0;
}

// fp32 -> bf16 (RNE) streaming convert, 8 elems/thread
__global__ void k_cvt(const float* __restrict__ in, ushort* __restrict__ outp, int n8) {
  int i = blockIdx.x * blockDim.x + threadIdx.x;
  if (i >= n8) return;
  const float4* ip = (const float4*)(in + (size_t)i * 8);
  float4 a = ip[0], b = ip[1];
  uint p0 = (uint)bf16_rne(a.x) | ((uint)bf16_rne(a.y) << 16);
  uint p1 = (uint)bf16_rne(a.z) | ((uint)bf16_rne(a.w) << 16);
  uint p2 = (uint)bf16_rne(b.x) | ((uint)bf16_rne(b.y) << 16);
  uint p3 = (uint)bf16_rne(b.z) | ((uint)bf16_rne(b.w) << 16);
  ((uint4*)outp)[i] = make_uint4(p0, p1, p2, p3);
}

// ---------------- CSR build ----------------

// histogram + per-edge rank (ushort ranks; 4 atomics in flight)
__global__ void k_count_rank(const int* __restrict__ dst, int* __restrict__ cnt,
                             ushort* __restrict__ rank, int e) {
  int i0 = (blockIdx.x * blockDim.x + threadIdx.x) * 4;
  if (i0 >= e) return;
  int d[4], r[4];
  if (i0 + 3 < e) {
    int4 dv = *(const int4*)(dst + i0);
    d[0] = dv.x; d[1] = dv.y; d[2] = dv.z; d[3] = dv.w;
  } else {
#pragma unroll
    for (int j = 0; j < 4; ++j) d[j] = (i0 + j < e) ? dst[i0 + j] : 0;
  }
#pragma unroll
  for (int j = 0; j < 4; ++j)
    if (i0 + j < e) r[j] = atomicAdd(&cnt[d[j]], 1);
  if (i0 + 3 < e) {
    ushort4 rv;
    rv.x = (ushort)r[0]; rv.y = (ushort)r[1];
    rv.z = (ushort)r[2]; rv.w = (ushort)r[3];
    *(ushort4*)(rank + i0) = rv;
  } else {
#pragma unroll
    for (int j = 0; j < 4; ++j)
      if (i0 + j < e) rank[i0 + j] = (ushort)r[j];
  }
}

#define SCAN_BS 256
#define SCAN_VPT 4
#define SCAN_CHUNK (SCAN_BS * SCAN_VPT)

__global__ __launch_bounds__(SCAN_BS) void k_blocksum(const int* __restrict__ cnt,
                                                      int* __restrict__ partial, int n) {
  __shared__ int s[SCAN_BS / 64];
  const int tid = threadIdx.x;
  const int base = blockIdx.x * SCAN_CHUNK;
  int sum = 0;
#pragma unroll
  for (int j = 0; j < SCAN_VPT; ++j) {
    int i = base + tid + j * SCAN_BS;
    if (i < n) sum += cnt[i];
  }
#pragma unroll
  for (int off = 32; off > 0; off >>= 1) sum += __shfl_down(sum, off, 64);
  if ((tid & 63) == 0) s[tid >> 6] = sum;
  __syncthreads();
  if (tid == 0) {
    int t = 0;
#pragma unroll
    for (int w = 0; w < SCAN_BS / 64; ++w) t += s[w];
    partial[blockIdx.x] = t;
  }
}

__global__ __launch_bounds__(256) void k_scan_partials(int* __restrict__ partial, int p,
                                                       int* __restrict__ row_ptr, int n_nodes) {
  __shared__ int s[256];
  const int tid = threadIdx.x;
  int carry = 0;
  for (int base = 0; base < p; base += 256) {
    int i = base + tid;
    int v = (i < p) ? partial[i] : 0;
    s[tid] = v;
    __syncthreads();
    for (int off = 1; off < 256; off <<= 1) {
      int t = (tid >= off) ? s[tid - off] : 0;
      __syncthreads();
      s[tid] += t;
      __syncthreads();
    }
    if (i < p) partial[i] = carry + s[tid] - v;  // exclusive
    int tot = s[255];
    __syncthreads();
    carry += tot;
  }
  if (tid == 0) row_ptr[n_nodes] = carry;
}

__global__ __launch_bounds__(SCAN_BS) void k_scatter(const int* __restrict__ cnt,
                                                     const int* __restrict__ partial,
                                                     int* __restrict__ row_ptr,
                                                     float* __restrict__ inv, int n) {
  __shared__ int s[SCAN_BS];
  const int tid = threadIdx.x;
  const int base = blockIdx.x * SCAN_CHUNK;
  const int i0 = base + tid * SCAN_VPT;
  int v[SCAN_VPT];
  int cv[SCAN_VPT];
  int sum = 0;
#pragma unroll
  for (int j = 0; j < SCAN_VPT; ++j) {
    int i = i0 + j;
    int c = (i < n) ? cnt[i] : 0;
    cv[j] = c;
    v[j] = sum;
    sum += c;
  }
  s[tid] = sum;
  __syncthreads();
  for (int off = 1; off < SCAN_BS; off <<= 1) {
    int t = (tid >= off) ? s[tid - off] : 0;
    __syncthreads();
    s[tid] += t;
    __syncthreads();
  }
  const int excl = partial[blockIdx.x] + s[tid] - sum;
#pragma unroll
  for (int j = 0; j < SCAN_VPT; ++j) {
    int i = i0 + j;
    if (i < n) {
      row_ptr[i] = excl + v[j];
      inv[i] = 1.0f / (float)(cv[j] > 1 ? cv[j] : 1);
    }
  }
}

// place edges: csr16[row_ptr[dst] + rank] = (ushort)src ; no atomics
__global__ void k_place(const int* __restrict__ src, const int* __restrict__ dst,
                        const ushort* __restrict__ rank, const int* __restrict__ row_ptr,
                        ushort* __restrict__ csr16, int e) {
  int i0 = (blockIdx.x * blockDim.x + threadIdx.x) * 4;
  if (i0 >= e) return;
  if (i0 + 3 < e) {
    int4 dv = *(const int4*)(dst + i0);
    int4 sv = *(const int4*)(src + i0);
    ushort4 rv = *(const ushort4*)(rank + i0);
    int p0 = row_ptr[dv.x], p1 = row_ptr[dv.y], p2 = row_ptr[dv.z], p3 = row_ptr[dv.w];
    csr16[p0 + rv.x] = (ushort)sv.x;
    csr16[p1 + rv.y] = (ushort)sv.y;
    csr16[p2 + rv.z] = (ushort)sv.z;
    csr16[p3 + rv.w] = (ushort)sv.w;
  } else {
#pragma unroll
    for (int j = 0; j < 4; ++j) {
      int i = i0 + j;
      if (i < e) csr16[row_ptr[dst[i]] + rank[i]] = (ushort)src[i];
    }
  }
}

// -------- weight pack: fp32 W -> RNE bf16, MFMA-B-fragment order -------------
template <int FOUT>
__global__ void k_pack(const float* __restrict__ Wl, const float* __restrict__ Wr,
                       ushort* __restrict__ hi) {
  constexpr int NCOL = 2 * FOUT;
  constexpr int NCHUNK = 4 * NCOL * 4;
  int ct = blockIdx.x * 256 + threadIdx.x;
  if (ct >= NCHUNK) return;
  const int g = ct & 3;
  const int nn = (ct >> 2) % NCOL;
  const int kt = ct / (4 * NCOL);
  uint hw[4];
#pragma unroll
  for (int w = 0; w < 4; ++w) {
    uint h2[2];
#pragma unroll
    for (int t = 0; t < 2; ++t) {
      int j = 2 * w + t;
      int k = kt * 32 + g * 8 + j;
      float v = (nn < FOUT) ? Wl[k * FOUT + nn] : Wr[k * FOUT + (nn - FOUT)];
      h2[t] = (uint)bf16_rne(v);
    }
    hw[w] = h2[0] | (h2[1] << 16);
  }
  ((uint4*)hi)[ct] = make_uint4(hw[0], hw[1], hw[2], hw[3]);
}

// -------- all layers: A bf16 x W bf16, LDS-staged, weight-prefetch pipeline --
// Zb(bf16) = A@Wl ; Rb(bf16) = A@Wr + b
// Weight loads for kt=0 are issued BEFORE the barrier (independent of LDS);
// inside the unrolled loop, kt+1's loads are issued before kt's MFMAs, so
// every L2 weight fetch hides under a full MFMA+ds_read block.
template <int FOUT>
__global__ __launch_bounds__(256) void k_gemm2b(const ushort* __restrict__ Hb,
                                                const ushort* __restrict__ Whi,
                                                const float* __restrict__ bias,
                                                ushort* __restrict__ Zb,
                                                ushort* __restrict__ Rb, int n) {
  constexpr int NCOL = 2 * FOUT;
  constexpr int NT = NCOL / 64;
  constexpr int MT = 2;
  __shared__ uint4 sA[32 * 16];  // 8KB: 32 rows x 16 slots of 16B

  const int tid = threadIdx.x;
  const int lane = tid & 63;
  const int wave = tid >> 6;
  const int row0 = blockIdx.x * 32;

  const int n0 = wave * (NCOL / 4);
  const int g16 = lane >> 4;
  const int l16 = lane & 15;

#pragma unroll
  for (int c = tid; c < 512; c += 256) {
    int srow = c >> 4, col16 = c & 15;
    int g = row0 + srow;
    uint4 v = make_uint4(0u, 0u, 0u, 0u);
    if (g < n) v = *(const uint4*)(Hb + (size_t)g * 128 + col16 * 8);
    sA[srow * 16 + (col16 ^ (srow & 7))] = v;
  }

  // prefetch kt=0 weights (independent of LDS; issued before the barrier)
  short8 bh[NT], bhN[NT];
#pragma unroll
  for (int nt = 0; nt < NT; ++nt) {
    size_t chunk = (size_t)(0 * NCOL + n0 + nt * 16 + l16) * 4 + g16;
    bh[nt] = *(const short8*)(Whi + chunk * 8);
  }
  __syncthreads();

  f32x4 acc[MT][NT];
#pragma unroll
  for (int mt = 0; mt < MT; ++mt)
#pragma unroll
    for (int nt = 0; nt < NT; ++nt) acc[mt][nt] = (f32x4)(0.f);

#pragma unroll
  for (int kt = 0; kt < 4; ++kt) {
    short8 a[MT];
#pragma unroll
    for (int mt = 0; mt < MT; ++mt) {
      int row = mt * 16 + l16;
      int slot = (kt * 4 + g16) ^ (row & 7);
      a[mt] = *(const short8*)&sA[row * 16 + slot];
    }
    if (kt < 3) {
#pragma unroll
      for (int nt = 0; nt < NT; ++nt) {
        size_t chunk = (size_t)((kt + 1) * NCOL + n0 + nt * 16 + l16) * 4 + g16;
        bhN[nt] = *(const short8*)(Whi + chunk * 8);
      }
    }
#pragma unroll
    for (int mt = 0; mt < MT; ++mt)
#pragma unroll
      for (int nt = 0; nt < NT; ++nt)
        acc[mt][nt] = __builtin_amdgcn_mfma_f32_16x16x32_bf16(a[mt], bh[nt], acc[mt][nt], 0, 0, 0);
    if (kt < 3) {
#pragma unroll
      for (int nt = 0; nt < NT; ++nt) bh[nt] = bhN[nt];
    }
  }

#pragma unroll
  for (int nt = 0; nt < NT; ++nt) {
    int col = n0 + nt * 16 + l16;
    bool isR = col >= FOUT;
    int cw = isR ? col - FOUT : col;
    float badd = isR ? bias[cw] : 0.f;
    ushort* base = isR ? Rb : Zb;
#pragma unroll
    for (int mt = 0; mt < MT; ++mt) {
#pragma unroll
      for (int j = 0; j < 4; ++j) {
        int row = row0 + mt * 16 + g16 * 4 + j;
        if (row < n) base[(size_t)row * FOUT + cw] = bf16_rne(acc[mt][nt][j] + badd);
      }
    }
  }
}

// -------- CSR mean-aggregation + epilogue: out = act(mean(Zb)*inv + Rb) ------
// OUTB: write bf16 H (16B/lane) for middle layers; fp32 for the final output.
template <int FOUT, bool RELU, bool OUTB>
__global__ __launch_bounds__(256) void k_agg2(const ushort* __restrict__ Zb,
                                              const ushort* __restrict__ Rb,
                                              const int* __restrict__ row_ptr,
                                              const ushort* __restrict__ csr16,
                                              const float* __restrict__ inv,
                                              void* __restrict__ outp, int n) {
  constexpr int FL = FOUT / 8;  // lanes per row (16 or 8)
  constexpr int EG = 64 / FL;   // edge groups per wave (4 or 8)
  const int lane = threadIdx.x & 63;
  const int node = blockIdx.x * 4 + (threadIdx.x >> 6);
  if (node >= n) return;
  const int c = lane % FL;
  const int eg = lane / FL;

  const int e0 = row_ptr[node];
  const int m = row_ptr[node + 1] - e0;  // wave-uniform
  const uint4* Z4 = (const uint4*)Zb;    // 16B = 8 bf16

  float acc[8];
#pragma unroll
  for (int k = 0; k < 8; ++k) acc[k] = 0.f;

  int t = eg;
  while (t < m) {
    int ss[4];
#pragma unroll
    for (int j = 0; j < 4; ++j) {
      int tj = t + j * EG;
      int tc = (tj < m) ? tj : (m - 1);  // clamped: always valid
      ss[j] = csr16[e0 + tc];
    }
    uint4 z[4];
#pragma unroll
    for (int j = 0; j < 4; ++j) z[j] = Z4[(size_t)ss[j] * FL + c];
#pragma unroll
    for (int j = 0; j < 4; ++j) {
      if (t + j * EG < m) {
        const uint* zw = (const uint*)&z[j];
#pragma unroll
        for (int w = 0; w < 4; ++w) {
          acc[2 * w]     += __uint_as_float(zw[w] << 16);
          acc[2 * w + 1] += __uint_as_float(zw[w] & 0xFFFF0000u);
        }
      }
    }
    t += 4 * EG;
  }

#pragma unroll
  for (int off = FL; off < 64; off <<= 1) {
#pragma unroll
    for (int k = 0; k < 8; ++k) acc[k] += __shfl_xor(acc[k], off, 64);
  }

  if (eg == 0) {
    const float iv = inv[node];
    uint4 rw = ((const uint4*)Rb)[(size_t)node * FL + c];
    const uint* rp = (const uint*)&rw;
    float o[8];
#pragma unroll
    for (int w = 0; w < 4; ++w) {
      o[2 * w]     = fmaf(acc[2 * w],     iv, __uint_as_float(rp[w] << 16));
      o[2 * w + 1] = fmaf(acc[2 * w + 1], iv, __uint_as_float(rp[w] & 0xFFFF0000u));
    }
    if (RELU) {
#pragma unroll
      for (int k = 0; k < 8; ++k) o[k] = fmaxf(o[k], 0.f);
    }
    if (OUTB) {
      uint p[4];
#pragma unroll
      for (int w = 0; w < 4; ++w)
        p[w] = (uint)bf16_rne(o[2 * w]) | ((uint)bf16_rne(o[2 * w + 1]) << 16);
      ((uint4*)outp)[(size_t)node * FL + c] = make_uint4(p[0], p[1], p[2], p[3]);
    } else {
      float4* op = (float4*)((float*)outp + (size_t)node * FOUT + c * 8);
      op[0] = make_float4(o[0], o[1], o[2], o[3]);
      op[1] = make_float4(o[4], o[5], o[6], o[7]);
    }
  }
}

// ---------------- launch ----------------

extern "C" void kernel_launch(void* const* d_in, const int* in_sizes, int n_in,
                              void* d_out, int out_size, void* d_ws, size_t ws_size,
                              hipStream_t stream) {
  const float* x   = (const float*)d_in[0];
  const int*   ei  = (const int*)d_in[1];
  const float* Wl0 = (const float*)d_in[2];
  const float* bl0 = (const float*)d_in[3];
  const float* Wr0 = (const float*)d_in[4];
  const float* Wl1 = (const float*)d_in[5];
  const float* bl1 = (const float*)d_in[6];
  const float* Wr1 = (const float*)d_in[7];
  const float* Wl2 = (const float*)d_in[8];
  const float* bl2 = (const float*)d_in[9];
  const float* Wr2 = (const float*)d_in[10];
  float* out = (float*)d_out;

  const int N = in_sizes[0] / 128;
  const int E = in_sizes[1] / 2;
  const int* src = ei;
  const int* dst = ei + E;

  char* w = (char*)d_ws;
  auto alloc = [&](size_t bytes) {
    char* p = w;
    w += (bytes + 255) & ~(size_t)255;
    return p;
  };
  int*    cnt     = (int*)alloc((size_t)N * 4);
  int*    row_ptr = (int*)alloc((size_t)(N + 1) * 4);
  ushort* rank    = (ushort*)alloc((size_t)E * 2 + 256);
  ushort* csr16   = (ushort*)alloc((size_t)E * 2 + 256);
  float*  inv     = (float*)alloc((size_t)N * 4);
  int*    partial = (int*)alloc((size_t)ceil_div(N, SCAN_CHUNK) * 4 + 256);
  ushort* Whi0    = (ushort*)alloc((size_t)4 * 256 * 4 * 16);
  ushort* Whi1    = (ushort*)alloc((size_t)4 * 256 * 4 * 16);
  ushort* Whi2    = (ushort*)alloc((size_t)4 * 128 * 4 * 16);
  ushort* XB      = (ushort*)alloc((size_t)N * 128 * 2);  // x in bf16
  ushort* BZ      = (ushort*)alloc((size_t)N * 128 * 2);
  ushort* BRb     = (ushort*)alloc((size_t)N * 128 * 2);  // R in bf16
  ushort* B0      = (ushort*)alloc((size_t)N * 128 * 2);  // H in bf16
  (void)ws_size; (void)n_in; (void)out_size;

  const int P = ceil_div(N, SCAN_CHUNK);

  // ---- weight packs + x convert ----
  k_pack<128><<<16, 256, 0, stream>>>(Wl0, Wr0, Whi0);
  k_pack<128><<<16, 256, 0, stream>>>(Wl1, Wr1, Whi1);
  k_pack<64><<<8, 256, 0, stream>>>(Wl2, Wr2, Whi2);
  k_cvt<<<ceil_div(N * 16, 256), 256, 0, stream>>>(x, XB, N * 16);

  // ---- CSR build (rank-based, single atomic pass) ----
  k_zero_int<<<ceil_div(N, 256), 256, 0, stream>>>(cnt, N);
  k_count_rank<<<ceil_div(E, 1024), 256, 0, stream>>>(dst, cnt, rank, E);
  k_blocksum<<<P, SCAN_BS, 0, stream>>>(cnt, partial, N);
  k_scan_partials<<<1, 256, 0, stream>>>(partial, P, row_ptr, N);
  k_scatter<<<P, SCAN_BS, 0, stream>>>(cnt, partial, row_ptr, inv, N);
  k_place<<<ceil_div(E, 1024), 256, 0, stream>>>(src, dst, rank, row_ptr, csr16, E);

  // ---- layer 0: xb -> (Zb,Rb) -> H1 bf16 (B0) ----
  k_gemm2b<128><<<ceil_div(N, 32), 256, 0, stream>>>(XB, Whi0, bl0, BZ, BRb, N);
  k_agg2<128, true, true><<<ceil_div(N, 4), 256, 0, stream>>>(BZ, BRb, row_ptr, csr16, inv, B0, N);

  // ---- layer 1: H1 bf16 -> (Zb,Rb) -> H2 bf16 (B0) ----
  k_gemm2b<128><<<ceil_div(N, 32), 256, 0, stream>>>(B0, Whi1, bl1, BZ, BRb, N);
  k_agg2<128, true, true><<<ceil_div(N, 4), 256, 0, stream>>>(BZ, BRb, row_ptr, csr16, inv, B0, N);

  // ---- layer 2: H2 bf16 -> (Zb,Rb) 64-wide -> out fp32 ----
  k_gemm2b<64><<<ceil_div(N, 32), 256, 0, stream>>>(B0, Whi2, bl2, BZ, BRb, N);
  k_agg2<64, false, false><<<ceil_div(N, 4), 256, 0, stream>>>(BZ, BRb, row_ptr, csr16, inv, out, N);
}

// Round 15
// 213.165 us; speedup vs baseline: 1.1298x; 1.0357x over previous
//
#include <hip/hip_runtime.h>

static inline int ceil_div(int a, int b) { return (a + b - 1) / b; }

typedef __attribute__((ext_vector_type(8))) short short8;   // 8 bf16 = 4 VGPR
typedef __attribute__((ext_vector_type(4))) float f32x4;

__device__ __forceinline__ ushort bf16_rne(float v) {
  uint u = __float_as_uint(v);
  return (ushort)((u + 0x7FFFu + ((u >> 16) & 1u)) >> 16);
}

// -------- weight pack (device): fp32 W -> RNE bf16, MFMA-B-fragment order ----
__device__ __forceinline__ void pack_dev(const float* __restrict__ Wl,
                                         const float* __restrict__ Wr,
                                         ushort* __restrict__ hi, int ct, int FOUT) {
  const int NCOL = 2 * FOUT;
  const int g = ct & 3;
  const int nn = (ct >> 2) % NCOL;
  const int kt = ct / (4 * NCOL);
  uint hw[4];
#pragma unroll
  for (int w = 0; w < 4; ++w) {
    uint h2[2];
#pragma unroll
    for (int t = 0; t < 2; ++t) {
      int j = 2 * w + t;
      int k = kt * 32 + g * 8 + j;
      float v = (nn < FOUT) ? Wl[k * FOUT + nn] : Wr[k * FOUT + (nn - FOUT)];
      h2[t] = (uint)bf16_rne(v);
    }
    hw[w] = h2[0] | (h2[1] << 16);
  }
  ((uint4*)hi)[ct] = make_uint4(hw[0], hw[1], hw[2], hw[3]);
}

// ==== prep mega-kernel: [0,16) pack0 | [16,32) pack1 | [32,40) pack2 |
//      [40,40+zb) zero cnt+flags | rest: x fp32->bf16 convert ================
__global__ void k_prep(const float* __restrict__ Wl0, const float* __restrict__ Wr0,
                       ushort* __restrict__ hi0,
                       const float* __restrict__ Wl1, const float* __restrict__ Wr1,
                       ushort* __restrict__ hi1,
                       const float* __restrict__ Wl2, const float* __restrict__ Wr2,
                       ushort* __restrict__ hi2,
                       const float* __restrict__ x, ushort* __restrict__ xb,
                       int* __restrict__ cnt, int* __restrict__ bflag,
                       int n, int zb) {
  const int b = blockIdx.x;
  const int tid = threadIdx.x;
  if (b < 16) {
    pack_dev(Wl0, Wr0, hi0, b * 256 + tid, 128);
  } else if (b < 32) {
    pack_dev(Wl1, Wr1, hi1, (b - 16) * 256 + tid, 128);
  } else if (b < 40) {
    pack_dev(Wl2, Wr2, hi2, (b - 32) * 256 + tid, 64);
  } else if (b < 40 + zb) {
    int b2 = b - 40;
    int i0 = b2 * 2048 + tid;
#pragma unroll
    for (int j = 0; j < 8; ++j) {
      int i = i0 + j * 256;
      if (i < n) cnt[i] = 0;
    }
    if (b2 == 0 && tid < 32) bflag[tid] = 0;
  } else {
    int i = (b - 40 - zb) * 256 + tid;
    if (i < n * 16) {
      const float4* ip = (const float4*)(x + (size_t)i * 8);
      float4 a = ip[0], bb = ip[1];
      uint p0 = (uint)bf16_rne(a.x) | ((uint)bf16_rne(a.y) << 16);
      uint p1 = (uint)bf16_rne(a.z) | ((uint)bf16_rne(a.w) << 16);
      uint p2 = (uint)bf16_rne(bb.x) | ((uint)bf16_rne(bb.y) << 16);
      uint p3 = (uint)bf16_rne(bb.z) | ((uint)bf16_rne(bb.w) << 16);
      ((uint4*)xb)[i] = make_uint4(p0, p1, p2, p3);
    }
  }
}

// ---------------- CSR build ----------------

// histogram + per-edge rank (ushort ranks; 4 atomics in flight)
__global__ void k_count_rank(const int* __restrict__ dst, int* __restrict__ cnt,
                             ushort* __restrict__ rank, int e) {
  int i0 = (blockIdx.x * blockDim.x + threadIdx.x) * 4;
  if (i0 >= e) return;
  int d[4], r[4];
  if (i0 + 3 < e) {
    int4 dv = *(const int4*)(dst + i0);
    d[0] = dv.x; d[1] = dv.y; d[2] = dv.z; d[3] = dv.w;
  } else {
#pragma unroll
    for (int j = 0; j < 4; ++j) d[j] = (i0 + j < e) ? dst[i0 + j] : 0;
  }
#pragma unroll
  for (int j = 0; j < 4; ++j)
    if (i0 + j < e) r[j] = atomicAdd(&cnt[d[j]], 1);
  if (i0 + 3 < e) {
    ushort4 rv;
    rv.x = (ushort)r[0]; rv.y = (ushort)r[1];
    rv.z = (ushort)r[2]; rv.w = (ushort)r[3];
    *(ushort4*)(rank + i0) = rv;
  } else {
#pragma unroll
    for (int j = 0; j < 4; ++j)
      if (i0 + j < e) rank[i0 + j] = (ushort)r[j];
  }
}

// ---- single-kernel scan, decoupled lookback: row_ptr (exclusive) + inv ------
// flag[b] = 0 (not ready) or block_total+1; the value rides the atomic, so no
// separate fence/array is needed. All blocks co-resident (<=32) -> no deadlock.
#define SCAN_BS 256
#define SCAN_VPT 8
#define SCAN_CHUNK (SCAN_BS * SCAN_VPT)

__global__ __launch_bounds__(SCAN_BS) void k_scan_lb(const int* __restrict__ cnt,
                                                     int* __restrict__ row_ptr,
                                                     float* __restrict__ inv,
                                                     int* __restrict__ bflag,
                                                     int n, int nblocks) {
  __shared__ int s[SCAN_BS];
  __shared__ int s_prev;
  const int tid = threadIdx.x;
  const int bid = blockIdx.x;
  const int i0 = bid * SCAN_CHUNK + tid * SCAN_VPT;
  int v[SCAN_VPT], cv[SCAN_VPT];
  int sum = 0;
#pragma unroll
  for (int j = 0; j < SCAN_VPT; ++j) {
    int i = i0 + j;
    int c = (i < n) ? cnt[i] : 0;
    cv[j] = c;
    v[j] = sum;
    sum += c;
  }
  s[tid] = sum;
  __syncthreads();
  for (int off = 1; off < SCAN_BS; off <<= 1) {
    int t = (tid >= off) ? s[tid - off] : 0;
    __syncthreads();
    s[tid] += t;
    __syncthreads();
  }
  const int btotal = s[SCAN_BS - 1];
  if (tid == 0) {
    atomicExch(&bflag[bid], btotal + 1);  // publish (value carries the sum)
    int prev = 0;
    for (int b = 0; b < bid; ++b) {
      int f;
      do { f = atomicAdd(&bflag[b], 0); } while (f == 0);
      prev += f - 1;
    }
    s_prev = prev;
    if (bid == nblocks - 1) row_ptr[n] = prev + btotal;
  }
  __syncthreads();
  const int excl = s_prev + s[tid] - sum;
#pragma unroll
  for (int j = 0; j < SCAN_VPT; ++j) {
    int i = i0 + j;
    if (i < n) {
      row_ptr[i] = excl + v[j];
      inv[i] = 1.0f / (float)(cv[j] > 1 ? cv[j] : 1);
    }
  }
}

// place edges: csr16[row_ptr[dst] + rank] = (ushort)src ; no atomics
__global__ void k_place(const int* __restrict__ src, const int* __restrict__ dst,
                        const ushort* __restrict__ rank, const int* __restrict__ row_ptr,
                        ushort* __restrict__ csr16, int e) {
  int i0 = (blockIdx.x * blockDim.x + threadIdx.x) * 4;
  if (i0 >= e) return;
  if (i0 + 3 < e) {
    int4 dv = *(const int4*)(dst + i0);
    int4 sv = *(const int4*)(src + i0);
    ushort4 rv = *(const ushort4*)(rank + i0);
    int p0 = row_ptr[dv.x], p1 = row_ptr[dv.y], p2 = row_ptr[dv.z], p3 = row_ptr[dv.w];
    csr16[p0 + rv.x] = (ushort)sv.x;
    csr16[p1 + rv.y] = (ushort)sv.y;
    csr16[p2 + rv.z] = (ushort)sv.z;
    csr16[p3 + rv.w] = (ushort)sv.w;
  } else {
#pragma unroll
    for (int j = 0; j < 4; ++j) {
      int i = i0 + j;
      if (i < e) csr16[row_ptr[dst[i]] + rank[i]] = (ushort)src[i];
    }
  }
}

// -------- all layers: A bf16 x W bf16, LDS-staged, weight-prefetch pipeline --
template <int FOUT>
__global__ __launch_bounds__(256) void k_gemm2b(const ushort* __restrict__ Hb,
                                                const ushort* __restrict__ Whi,
                                                const float* __restrict__ bias,
                                                ushort* __restrict__ Zb,
                                                ushort* __restrict__ Rb, int n) {
  constexpr int NCOL = 2 * FOUT;
  constexpr int NT = NCOL / 64;
  constexpr int MT = 2;
  __shared__ uint4 sA[32 * 16];  // 8KB: 32 rows x 16 slots of 16B

  const int tid = threadIdx.x;
  const int lane = tid & 63;
  const int wave = tid >> 6;
  const int row0 = blockIdx.x * 32;

  const int n0 = wave * (NCOL / 4);
  const int g16 = lane >> 4;
  const int l16 = lane & 15;

#pragma unroll
  for (int c = tid; c < 512; c += 256) {
    int srow = c >> 4, col16 = c & 15;
    int g = row0 + srow;
    uint4 v = make_uint4(0u, 0u, 0u, 0u);
    if (g < n) v = *(const uint4*)(Hb + (size_t)g * 128 + col16 * 8);
    sA[srow * 16 + (col16 ^ (srow & 7))] = v;
  }

  // prefetch kt=0 weights (independent of LDS; issued before the barrier)
  short8 bh[NT], bhN[NT];
#pragma unroll
  for (int nt = 0; nt < NT; ++nt) {
    size_t chunk = (size_t)(0 * NCOL + n0 + nt * 16 + l16) * 4 + g16;
    bh[nt] = *(const short8*)(Whi + chunk * 8);
  }
  __syncthreads();

  f32x4 acc[MT][NT];
#pragma unroll
  for (int mt = 0; mt < MT; ++mt)
#pragma unroll
    for (int nt = 0; nt < NT; ++nt) acc[mt][nt] = (f32x4)(0.f);

#pragma unroll
  for (int kt = 0; kt < 4; ++kt) {
    short8 a[MT];
#pragma unroll
    for (int mt = 0; mt < MT; ++mt) {
      int row = mt * 16 + l16;
      int slot = (kt * 4 + g16) ^ (row & 7);
      a[mt] = *(const short8*)&sA[row * 16 + slot];
    }
    if (kt < 3) {
#pragma unroll
      for (int nt = 0; nt < NT; ++nt) {
        size_t chunk = (size_t)((kt + 1) * NCOL + n0 + nt * 16 + l16) * 4 + g16;
        bhN[nt] = *(const short8*)(Whi + chunk * 8);
      }
    }
#pragma unroll
    for (int mt = 0; mt < MT; ++mt)
#pragma unroll
      for (int nt = 0; nt < NT; ++nt)
        acc[mt][nt] = __builtin_amdgcn_mfma_f32_16x16x32_bf16(a[mt], bh[nt], acc[mt][nt], 0, 0, 0);
    if (kt < 3) {
#pragma unroll
      for (int nt = 0; nt < NT; ++nt) bh[nt] = bhN[nt];
    }
  }

#pragma unroll
  for (int nt = 0; nt < NT; ++nt) {
    int col = n0 + nt * 16 + l16;
    bool isR = col >= FOUT;
    int cw = isR ? col - FOUT : col;
    float badd = isR ? bias[cw] : 0.f;
    ushort* base = isR ? Rb : Zb;
#pragma unroll
    for (int mt = 0; mt < MT; ++mt) {
#pragma unroll
      for (int j = 0; j < 4; ++j) {
        int row = row0 + mt * 16 + g16 * 4 + j;
        if (row < n) base[(size_t)row * FOUT + cw] = bf16_rne(acc[mt][nt][j] + badd);
      }
    }
  }
}

// -------- CSR mean-aggregation + epilogue: out = act(mean(Zb)*inv + Rb) ------
// DEPTH=8 for F=128 (32 edges in flight/wave, matching F=64's 32).
template <int FOUT, bool RELU, bool OUTB>
__global__ __launch_bounds__(256) void k_agg2(const ushort* __restrict__ Zb,
                                              const ushort* __restrict__ Rb,
                                              const int* __restrict__ row_ptr,
                                              const ushort* __restrict__ csr16,
                                              const float* __restrict__ inv,
                                              void* __restrict__ outp, int n) {
  constexpr int FL = FOUT / 8;            // lanes per row (16 or 8)
  constexpr int EG = 64 / FL;             // edge groups per wave (4 or 8)
  constexpr int DEPTH = (FL == 16) ? 8 : 4;
  const int lane = threadIdx.x & 63;
  const int node = blockIdx.x * 4 + (threadIdx.x >> 6);
  if (node >= n) return;
  const int c = lane % FL;
  const int eg = lane / FL;

  const int e0 = row_ptr[node];
  const int m = row_ptr[node + 1] - e0;  // wave-uniform
  const uint4* Z4 = (const uint4*)Zb;    // 16B = 8 bf16

  float acc[8];
#pragma unroll
  for (int k = 0; k < 8; ++k) acc[k] = 0.f;

  int t = eg;
  while (t < m) {
    int ss[DEPTH];
#pragma unroll
    for (int j = 0; j < DEPTH; ++j) {
      int tj = t + j * EG;
      int tc = (tj < m) ? tj : (m - 1);  // clamped: always valid
      ss[j] = csr16[e0 + tc];
    }
    uint4 z[DEPTH];
#pragma unroll
    for (int j = 0; j < DEPTH; ++j) z[j] = Z4[(size_t)ss[j] * FL + c];
#pragma unroll
    for (int j = 0; j < DEPTH; ++j) {
      if (t + j * EG < m) {
        const uint* zw = (const uint*)&z[j];
#pragma unroll
        for (int w = 0; w < 4; ++w) {
          acc[2 * w]     += __uint_as_float(zw[w] << 16);
          acc[2 * w + 1] += __uint_as_float(zw[w] & 0xFFFF0000u);
        }
      }
    }
    t += DEPTH * EG;
  }

#pragma unroll
  for (int off = FL; off < 64; off <<= 1) {
#pragma unroll
    for (int k = 0; k < 8; ++k) acc[k] += __shfl_xor(acc[k], off, 64);
  }

  if (eg == 0) {
    const float iv = inv[node];
    uint4 rw = ((const uint4*)Rb)[(size_t)node * FL + c];
    const uint* rp = (const uint*)&rw;
    float o[8];
#pragma unroll
    for (int w = 0; w < 4; ++w) {
      o[2 * w]     = fmaf(acc[2 * w],     iv, __uint_as_float(rp[w] << 16));
      o[2 * w + 1] = fmaf(acc[2 * w + 1], iv, __uint_as_float(rp[w] & 0xFFFF0000u));
    }
    if (RELU) {
#pragma unroll
      for (int k = 0; k < 8; ++k) o[k] = fmaxf(o[k], 0.f);
    }
    if (OUTB) {
      uint p[4];
#pragma unroll
      for (int w = 0; w < 4; ++w)
        p[w] = (uint)bf16_rne(o[2 * w]) | ((uint)bf16_rne(o[2 * w + 1]) << 16);
      ((uint4*)outp)[(size_t)node * FL + c] = make_uint4(p[0], p[1], p[2], p[3]);
    } else {
      float4* op = (float4*)((float*)outp + (size_t)node * FOUT + c * 8);
      op[0] = make_float4(o[0], o[1], o[2], o[3]);
      op[1] = make_float4(o[4], o[5], o[6], o[7]);
    }
  }
}

// ---------------- launch ----------------

extern "C" void kernel_launch(void* const* d_in, const int* in_sizes, int n_in,
                              void* d_out, int out_size, void* d_ws, size_t ws_size,
                              hipStream_t stream) {
  const float* x   = (const float*)d_in[0];
  const int*   ei  = (const int*)d_in[1];
  const float* Wl0 = (const float*)d_in[2];
  const float* bl0 = (const float*)d_in[3];
  const float* Wr0 = (const float*)d_in[4];
  const float* Wl1 = (const float*)d_in[5];
  const float* bl1 = (const float*)d_in[6];
  const float* Wr1 = (const float*)d_in[7];
  const float* Wl2 = (const float*)d_in[8];
  const float* bl2 = (const float*)d_in[9];
  const float* Wr2 = (const float*)d_in[10];
  float* out = (float*)d_out;

  const int N = in_sizes[0] / 128;
  const int E = in_sizes[1] / 2;
  const int* src = ei;
  const int* dst = ei + E;

  char* w = (char*)d_ws;
  auto alloc = [&](size_t bytes) {
    char* p = w;
    w += (bytes + 255) & ~(size_t)255;
    return p;
  };
  int*    cnt     = (int*)alloc((size_t)N * 4);
  int*    row_ptr = (int*)alloc((size_t)(N + 1) * 4);
  int*    bflag   = (int*)alloc(32 * 4);
  ushort* rank    = (ushort*)alloc((size_t)E * 2 + 256);
  ushort* csr16   = (ushort*)alloc((size_t)E * 2 + 256);
  float*  inv     = (float*)alloc((size_t)N * 4);
  ushort* Whi0    = (ushort*)alloc((size_t)4 * 256 * 4 * 16);
  ushort* Whi1    = (ushort*)alloc((size_t)4 * 256 * 4 * 16);
  ushort* Whi2    = (ushort*)alloc((size_t)4 * 128 * 4 * 16);
  ushort* XB      = (ushort*)alloc((size_t)N * 128 * 2);  // x in bf16
  ushort* BZ      = (ushort*)alloc((size_t)N * 128 * 2);
  ushort* BRb     = (ushort*)alloc((size_t)N * 128 * 2);  // R in bf16
  ushort* B0      = (ushort*)alloc((size_t)N * 128 * 2);  // H in bf16
  (void)ws_size; (void)n_in; (void)out_size;

  const int ZB = ceil_div(N, 2048);             // zero-range blocks
  const int PS = ceil_div(N, SCAN_CHUNK);       // scan blocks (25 <= 32)
  const int PREP_B = 40 + ZB + ceil_div(N * 16, 256);

  // ---- prep: packs + cvt + zero (1 launch) ----
  k_prep<<<PREP_B, 256, 0, stream>>>(Wl0, Wr0, Whi0, Wl1, Wr1, Whi1,
                                     Wl2, Wr2, Whi2, x, XB, cnt, bflag, N, ZB);

  // ---- CSR build: count_rank -> lookback scan -> place (3 launches) ----
  k_count_rank<<<ceil_div(E, 1024), 256, 0, stream>>>(dst, cnt, rank, E);
  k_scan_lb<<<PS, SCAN_BS, 0, stream>>>(cnt, row_ptr, inv, bflag, N, PS);
  k_place<<<ceil_div(E, 1024), 256, 0, stream>>>(src, dst, rank, row_ptr, csr16, E);

  // ---- layer 0: xb -> (Zb,Rb) -> H1 bf16 (B0) ----
  k_gemm2b<128><<<ceil_div(N, 32), 256, 0, stream>>>(XB, Whi0, bl0, BZ, BRb, N);
  k_agg2<128, true, true><<<ceil_div(N, 4), 256, 0, stream>>>(BZ, BRb, row_ptr, csr16, inv, B0, N);

  // ---- layer 1: H1 bf16 -> (Zb,Rb) -> H2 bf16 (B0) ----
  k_gemm2b<128><<<ceil_div(N, 32), 256, 0, stream>>>(B0, Whi1, bl1, BZ, BRb, N);
  k_agg2<128, true, true><<<ceil_div(N, 4), 256, 0, stream>>>(BZ, BRb, row_ptr, csr16, inv, B0, N);

  // ---- layer 2: H2 bf16 -> (Zb,Rb) 64-wide -> out fp32 ----
  k_gemm2b<64><<<ceil_div(N, 32), 256, 0, stream>>>(B0, Whi2, bl2, BZ, BRb, N);
  k_agg2<64, false, false><<<ceil_div(N, 4), 256, 0, stream>>>(BZ, BRb, row_ptr, csr16, inv, out, N);
}